// Round 14
// baseline (213.574 us; speedup 1.0000x reference)
//
#include <hip/hip_runtime.h>

#define BB 8
#define ENC_C 64
#define DEC_C 128
#define HH 128
#define WW 128

typedef unsigned short ushort_t;
typedef __attribute__((ext_vector_type(8))) short short8;
typedef __attribute__((ext_vector_type(4))) float f32x4;

static __device__ __forceinline__ ushort_t f2bf(float x) {
  unsigned int u = __builtin_bit_cast(unsigned int, x);
  u += 0x7fff + ((u >> 16) & 1);   // round-to-nearest-even
  return (ushort_t)(u >> 16);
}
static __device__ __forceinline__ float bf2f(ushort_t v) {
  unsigned int u = ((unsigned int)v) << 16;
  return __builtin_bit_cast(float, u);
}

// ---------------------------------------------------------------------------
// Kernel 0: pack weight fragments (bf16).
//   blk 0..143   : conv_w -> packedC  [tap][ds][nf]
//   blk 144..159 : W_attn -> packedA
//   blk 160..175 : W_dec  -> packedQ
//   blk 176..183 : W_enc  -> packedK
// Frag: lane l, elem j holds W[k = ks*32 + (l>>4)*8 + j][n = nf*16 + (l&15)].
// ---------------------------------------------------------------------------
__global__ __launch_bounds__(64) void pack_w_kernel(
    const float* __restrict__ conv_w, const float* __restrict__ W_attn,
    const float* __restrict__ W_dec, const float* __restrict__ W_enc,
    ushort_t* __restrict__ packedC, ushort_t* __restrict__ packedA,
    ushort_t* __restrict__ packedQ, ushort_t* __restrict__ packedK)
{
  const int blk = blockIdx.x;
  const int l = threadIdx.x;
  const float* W;
  ushort_t* dst;
  int bb;
  if (blk < 144) {
    const int kstep = blk >> 2, nf = blk & 3;
    const int tap = kstep >> 2, dstep = kstep & 3;
    const int n = nf * 16 + (l & 15);
    const int dbase = dstep * 32 + (l >> 4) * 8;
    ushort_t v[8];
    #pragma unroll
    for (int j = 0; j < 8; ++j)
      v[j] = f2bf(conv_w[(tap * DEC_C + dbase + j) * 64 + n]);
    ushort_t* d = packedC + (((long)tap * 16 + dstep * 4 + nf) * 64 + l) * 8;
    #pragma unroll
    for (int j = 0; j < 8; ++j) d[j] = v[j];
    return;
  } else if (blk < 160) {
    W = W_attn; dst = packedA; bb = blk - 144;
  } else if (blk < 176) {
    W = W_dec;  dst = packedQ; bb = blk - 160;
  } else {
    W = W_enc;  dst = packedK; bb = blk - 176;
  }
  const int ks = bb >> 2, nf = bb & 3;
  const int n = nf * 16 + (l & 15);
  const int kbase = ks * 32 + (l >> 4) * 8;
  ushort_t v[8];
  #pragma unroll
  for (int j = 0; j < 8; ++j)
    v[j] = f2bf(W[(kbase + j) * 64 + n]);
  ushort_t* d = dst + ((long)bb * 64 + l) * 8;
  #pragma unroll
  for (int j = 0; j < 8; ++j) d[j] = v[j];
}

// ---------------------------------------------------------------------------
// Kernel 1: per (b,h) row. MFMA (A = pixel frags from LDS, B = packed W).
// Outputs q/k NHWC bf16 (+bias), enc_t NHWC bf16, dec_t NHWC bf16.
// No waves-per-EU cap: R6 showed a VGPR cap here spills to scratch.
// ---------------------------------------------------------------------------
__global__ __launch_bounds__(256) void prep_kernel(
    const float* __restrict__ enc, const float* __restrict__ dec,
    const ushort_t* __restrict__ packedQ, const ushort_t* __restrict__ packedK,
    const float* __restrict__ b_enc, const float* __restrict__ b_dec,
    ushort_t* __restrict__ q_nhwc, ushort_t* __restrict__ k_nhwc,
    ushort_t* __restrict__ enc_t, ushort_t* __restrict__ dec_t)
{
  __shared__ float smem[WW * 68];
  const int bh = blockIdx.x;
  const int b = bh >> 7, h = bh & 127;
  const int tid = threadIdx.x;
  const int l = tid & 63;
  const int wv = tid >> 6;
  const int pix0 = wv * 32;
  const int col = l & 15, kg = l >> 4;

  // ---- encoder tile [w][c] f32 ----
  #pragma unroll
  for (int i = 0; i < 32; ++i) {
    int idx = tid + i * 256;
    int cc = idx >> 7, wl = idx & 127;
    smem[wl * 68 + cc] = enc[((b * ENC_C + cc) * HH + h) * WW + wl];
  }
  __syncthreads();

  // enc_t NHWC bf16
  #pragma unroll
  for (int i = 0; i < 32; ++i) {
    int idx = tid + i * 256;
    int wl = idx >> 6, cc = idx & 63;
    enc_t[((long)bh * WW + wl) * 64 + cc] = f2bf(smem[wl * 68 + cc]);
  }

  // k = enc @ W_enc  (A = pixels, D row = pixel -> NHWC)
  f32x4 acck[2][4];
  #pragma unroll
  for (int mf = 0; mf < 2; ++mf)
    #pragma unroll
    for (int nf = 0; nf < 4; ++nf)
      acck[mf][nf] = (f32x4){0.f, 0.f, 0.f, 0.f};

  #pragma unroll
  for (int ks = 0; ks < 2; ++ks) {
    short8 afr[2];
    #pragma unroll
    for (int mf = 0; mf < 2; ++mf) {
      const int pix = pix0 + mf * 16 + col;
      const float4* p = (const float4*)&smem[pix * 68 + ks * 32 + kg * 8];
      float4 x0 = p[0], x1 = p[1];
      short8 v;
      v[0] = (short)f2bf(x0.x); v[1] = (short)f2bf(x0.y);
      v[2] = (short)f2bf(x0.z); v[3] = (short)f2bf(x0.w);
      v[4] = (short)f2bf(x1.x); v[5] = (short)f2bf(x1.y);
      v[6] = (short)f2bf(x1.z); v[7] = (short)f2bf(x1.w);
      afr[mf] = v;
    }
    #pragma unroll
    for (int nf = 0; nf < 4; ++nf) {
      const short8 bfr =
          *(const short8*)(packedK + ((long)(ks * 4 + nf) * 64 + l) * 8);
      acck[0][nf] = __builtin_amdgcn_mfma_f32_16x16x32_bf16(
          afr[0], bfr, acck[0][nf], 0, 0, 0);
      acck[1][nf] = __builtin_amdgcn_mfma_f32_16x16x32_bf16(
          afr[1], bfr, acck[1][nf], 0, 0, 0);
    }
  }
  // store k NHWC bf16
  #pragma unroll
  for (int mf = 0; mf < 2; ++mf)
    #pragma unroll
    for (int nf = 0; nf < 4; ++nf)
      #pragma unroll
      for (int r = 0; r < 4; ++r) {
        const int pix = pix0 + mf * 16 + kg * 4 + r;
        const int c = nf * 16 + col;
        k_nhwc[((long)bh * WW + pix) * 64 + c] = f2bf(acck[mf][nf][r] + b_enc[c]);
      }
  __syncthreads();

  // ---- decoder tile, two 64-channel halves ----
  f32x4 accq[2][4];
  #pragma unroll
  for (int mf = 0; mf < 2; ++mf)
    #pragma unroll
    for (int nf = 0; nf < 4; ++nf)
      accq[mf][nf] = (f32x4){0.f, 0.f, 0.f, 0.f};

  #pragma unroll
  for (int hf = 0; hf < 2; ++hf) {
    #pragma unroll
    for (int i = 0; i < 32; ++i) {
      int idx = tid + i * 256;
      int cc = idx >> 7, wl = idx & 127;
      smem[wl * 68 + cc] = dec[((b * DEC_C + hf * 64 + cc) * HH + h) * WW + wl];
    }
    __syncthreads();

    // dec_t NHWC bf16
    #pragma unroll
    for (int i = 0; i < 32; ++i) {
      int idx = tid + i * 256;
      int wl = idx >> 6, cc = idx & 63;
      dec_t[((long)bh * WW + wl) * DEC_C + hf * 64 + cc] =
          f2bf(smem[wl * 68 + cc]);
    }

    #pragma unroll
    for (int ks2 = 0; ks2 < 2; ++ks2) {
      const int ks = hf * 2 + ks2;
      short8 afr[2];
      #pragma unroll
      for (int mf = 0; mf < 2; ++mf) {
        const int pix = pix0 + mf * 16 + col;
        const float4* p = (const float4*)&smem[pix * 68 + ks2 * 32 + kg * 8];
        float4 x0 = p[0], x1 = p[1];
        short8 v;
        v[0] = (short)f2bf(x0.x); v[1] = (short)f2bf(x0.y);
        v[2] = (short)f2bf(x0.z); v[3] = (short)f2bf(x0.w);
        v[4] = (short)f2bf(x1.x); v[5] = (short)f2bf(x1.y);
        v[6] = (short)f2bf(x1.z); v[7] = (short)f2bf(x1.w);
        afr[mf] = v;
      }
      #pragma unroll
      for (int nf = 0; nf < 4; ++nf) {
        const short8 bfr =
            *(const short8*)(packedQ + ((long)(ks * 4 + nf) * 64 + l) * 8);
        accq[0][nf] = __builtin_amdgcn_mfma_f32_16x16x32_bf16(
            afr[0], bfr, accq[0][nf], 0, 0, 0);
        accq[1][nf] = __builtin_amdgcn_mfma_f32_16x16x32_bf16(
            afr[1], bfr, accq[1][nf], 0, 0, 0);
      }
    }
    __syncthreads();
  }

  // store q NHWC bf16
  #pragma unroll
  for (int mf = 0; mf < 2; ++mf)
    #pragma unroll
    for (int nf = 0; nf < 4; ++nf)
      #pragma unroll
      for (int r = 0; r < 4; ++r) {
        const int pix = pix0 + mf * 16 + kg * 4 + r;
        const int c = nf * 16 + col;
        q_nhwc[((long)bh * WW + pix) * 64 + c] = f2bf(accq[mf][nf][r] + b_dec[c]);
      }
}

// ---------------------------------------------------------------------------
// Kernel 2: attention, FOUR threads per pixel (16 channels each).
// ---------------------------------------------------------------------------
__global__ __launch_bounds__(256) void attn_kernel(
    const ushort_t* __restrict__ q_nhwc, const ushort_t* __restrict__ k_nhwc,
    const ushort_t* __restrict__ enc_t, const float* __restrict__ W_agg,
    const float* __restrict__ b_agg, ushort_t* __restrict__ att)
{
  const int nwg = gridDim.x;                 // 2048, divisible by 8
  const int cpx = nwg >> 3;
  const int bid = blockIdx.x;
  const int swz = (bid & 7) * cpx + (bid >> 3);   // XCD-contiguous pixels
  const int t = swz * 256 + threadIdx.x;     // 0 .. 4*npix-1
  const int pix = t >> 2;
  const int cb = (t & 3) * 16;               // this thread's channel base
  const int h = (pix >> 7) & 127;
  const int w = pix & 127;

  int off[9]; bool valid[9];
  #pragma unroll
  for (int n = 0; n < 9; ++n) {
    const int dh = n / 3 - 1, dw = n % 3 - 1;
    const int nh = h + dh, nw = w + dw;
    valid[n] = (nh >= 0 && nh < HH && nw >= 0 && nw < WW);
    const int nhc = min(max(nh, 0), HH - 1);
    const int nwc = min(max(nw, 0), WW - 1);
    off[n] = (pix & ~16383) + nhc * WW + nwc;  // same batch, clamped pixel
  }

  const short8* qp = (const short8*)(q_nhwc + ((long)pix << 6) + cb);
  const short8 qa = qp[0], qb = qp[1];

  float wa[16];
  {
    float4 w0 = *(const float4*)(W_agg + cb);
    float4 w1 = *(const float4*)(W_agg + cb + 4);
    float4 w2 = *(const float4*)(W_agg + cb + 8);
    float4 w3 = *(const float4*)(W_agg + cb + 12);
    wa[0]=w0.x; wa[1]=w0.y; wa[2]=w0.z; wa[3]=w0.w;
    wa[4]=w1.x; wa[5]=w1.y; wa[6]=w1.z; wa[7]=w1.w;
    wa[8]=w2.x; wa[9]=w2.y; wa[10]=w2.z; wa[11]=w2.w;
    wa[12]=w3.x; wa[13]=w3.y; wa[14]=w3.z; wa[15]=w3.w;
  }

  // ---- score partials over this thread's 16 channels ----
  float s[9];
  #pragma unroll
  for (int n = 0; n < 9; ++n) {
    const short8* kp = (const short8*)(k_nhwc + ((long)off[n] << 6) + cb);
    const short8 ka = kp[0], kb = kp[1];
    float sc = 0.f;
    #pragma unroll
    for (int e = 0; e < 8; ++e) {
      float x = bf2f((ushort_t)qa[e]) + bf2f((ushort_t)ka[e]);
      x = fminf(fmaxf(x, -15.f), 15.f);
      float z = __builtin_amdgcn_exp2f(x * 2.88539008f);
      float tt = __builtin_fmaf(-2.f, __builtin_amdgcn_rcpf(z + 1.f), 1.f);
      sc = __builtin_fmaf(tt, wa[e], sc);
    }
    #pragma unroll
    for (int e = 0; e < 8; ++e) {
      float x = bf2f((ushort_t)qb[e]) + bf2f((ushort_t)kb[e]);
      x = fminf(fmaxf(x, -15.f), 15.f);
      float z = __builtin_amdgcn_exp2f(x * 2.88539008f);
      float tt = __builtin_fmaf(-2.f, __builtin_amdgcn_rcpf(z + 1.f), 1.f);
      sc = __builtin_fmaf(tt, wa[8 + e], sc);
    }
    s[n] = sc;
  }

  // ---- combine partials across the 4 lanes of this pixel ----
  #pragma unroll
  for (int n = 0; n < 9; ++n) {
    s[n] += __shfl_xor(s[n], 1);
    s[n] += __shfl_xor(s[n], 2);
  }

  // ---- masked softmax (duplicated in all 4 lanes) ----
  const float bagg = b_agg[0];
  float m = -1e30f;
  #pragma unroll
  for (int n = 0; n < 9; ++n) {
    s[n] = valid[n] ? (s[n] + bagg) : -1e30f;
    m = fmaxf(m, s[n]);
  }
  float attw[9]; float denom = 0.f;
  #pragma unroll
  for (int n = 0; n < 9; ++n) {
    attw[n] = __builtin_amdgcn_exp2f((s[n] - m) * 1.44269504f);
    denom += attw[n];
  }
  const float inv = __builtin_amdgcn_rcpf(denom);
  #pragma unroll
  for (int n = 0; n < 9; ++n) attw[n] *= inv;   // invalid -> exactly 0

  // ---- weighted encoder sum over this thread's 16 channels ----
  float a16[16];
  #pragma unroll
  for (int e = 0; e < 16; ++e) a16[e] = 0.f;
  #pragma unroll
  for (int n = 0; n < 9; ++n) {
    const short8* ep = (const short8*)(enc_t + ((long)off[n] << 6) + cb);
    const short8 ea = ep[0], eb = ep[1];
    #pragma unroll
    for (int e = 0; e < 8; ++e)
      a16[e] = __builtin_fmaf(attw[n], bf2f((ushort_t)ea[e]), a16[e]);
    #pragma unroll
    for (int e = 0; e < 8; ++e)
      a16[8 + e] = __builtin_fmaf(attw[n], bf2f((ushort_t)eb[e]), a16[8 + e]);
  }
  short8 o0, o1;
  #pragma unroll
  for (int e = 0; e < 8; ++e) {
    o0[e] = (short)f2bf(a16[e]);
    o1[e] = (short)f2bf(a16[8 + e]);
  }
  short8* op = (short8*)(att + ((long)pix << 6) + cb);
  op[0] = o0;
  op[1] = o1;
}

// ---------------------------------------------------------------------------
// Kernel 3: conv with REGISTER-RESIDENT B + out, one row/block (grid 1024).
// Wave = 16 output channels (nf = wave id): its 36 B-frags (9 taps x 4 ds,
// 144 VGPR) are loaded ONCE, then 8 tiles of 16 pixels run {12 A-loads ->
// 12 MFMAs} per kh with no barriers, no LDS, no B-reload. All 4 waves read
// identical A addresses (L1-shared). acc split (A/B) halves the MFMA chain.
// vals -> 18.4KB LDS bounce (1 barrier) -> R11 out-phase.
// ---------------------------------------------------------------------------
__global__ __launch_bounds__(256) void conv_out_kernel(
    const ushort_t* __restrict__ dec_t, const ushort_t* __restrict__ packedC,
    const float* __restrict__ conv_b, const ushort_t* __restrict__ attn_nhwc,
    const ushort_t* __restrict__ packedA, const float* __restrict__ b_attn,
    float* __restrict__ out)
{
  __shared__ ushort_t vlds[WW * 72];         // 18.4 KB
  const int nwg = gridDim.x;                 // 1024, divisible by 8
  const int cpx = nwg >> 3;
  const int bid = blockIdx.x;
  const int bh = (bid & 7) * cpx + (bid >> 3);
  const int b = bh >> 7, h = bh & 127;
  const int tid = threadIdx.x;
  const int l = tid & 63;
  const int wv = tid >> 6;                   // wave -> nf group
  const int col = l & 15, kg = l >> 4;

  // ---- load this wave's 36 B-frags into registers (one time) ----
  short8 bw[9][4];
  #pragma unroll
  for (int tap = 0; tap < 9; ++tap)
    #pragma unroll
    for (int ds = 0; ds < 4; ++ds)
      bw[tap][ds] = *(const short8*)(
          packedC + (((long)tap * 16 + ds * 4 + wv) * 64 + l) * 8);

  const float bias = conv_b[wv * 16 + col];

  // ---- conv: 8 tiles of 16 pixels, no barriers ----
  #pragma unroll 1
  for (int t = 0; t < 8; ++t) {
    const int tp = t * 16;
    f32x4 accA = (f32x4){0.f, 0.f, 0.f, 0.f};
    f32x4 accB = (f32x4){0.f, 0.f, 0.f, 0.f};

    #pragma unroll
    for (int kh = 0; kh < 3; ++kh) {
      const int hh = h + kh - 1;
      if (hh < 0 || hh >= HH) continue;      // block-uniform skip
      const ushort_t* arow = dec_t + ((long)(b * HH + hh) * WW) * DEC_C;

      short8 afr[3][4];
      #pragma unroll
      for (int kw = 0; kw < 3; ++kw) {
        const int wp = tp + col + kw - 1;
        const bool ok = (wp >= 0 && wp < WW);
        #pragma unroll
        for (int ds = 0; ds < 4; ++ds) {
          short8 z = {0, 0, 0, 0, 0, 0, 0, 0};
          afr[kw][ds] = ok
              ? *(const short8*)(arow + (long)wp * DEC_C + ds * 32 + kg * 8) : z;
        }
      }
      #pragma unroll
      for (int kw = 0; kw < 3; ++kw) {
        const int tap = kh * 3 + kw;
        accA = __builtin_amdgcn_mfma_f32_16x16x32_bf16(
            afr[kw][0], bw[tap][0], accA, 0, 0, 0);
        accB = __builtin_amdgcn_mfma_f32_16x16x32_bf16(
            afr[kw][1], bw[tap][1], accB, 0, 0, 0);
        accA = __builtin_amdgcn_mfma_f32_16x16x32_bf16(
            afr[kw][2], bw[tap][2], accA, 0, 0, 0);
        accB = __builtin_amdgcn_mfma_f32_16x16x32_bf16(
            afr[kw][3], bw[tap][3], accB, 0, 0, 0);
      }
    }

    // D tile: pixel = tp + kg*4 + r, ch = wv*16 + col
    #pragma unroll
    for (int r = 0; r < 4; ++r) {
      const int pix = tp + kg * 4 + r;
      vlds[pix * 72 + wv * 16 + col] = f2bf(accA[r] + accB[r] + bias);
    }
  }
  __syncthreads();

  // ---- out phase (swapped: A = W_attn frags, B = cat^T; D = (ch, pix)) ----
  const int pix0 = wv * 32;
  f32x4 ao[4][2];
  #pragma unroll
  for (int mf = 0; mf < 4; ++mf)
    #pragma unroll
    for (int pf = 0; pf < 2; ++pf)
      ao[mf][pf] = (f32x4){0.f, 0.f, 0.f, 0.f};

  #pragma unroll
  for (int ks = 0; ks < 4; ++ks) {
    short8 bfr[2];
    #pragma unroll
    for (int pf = 0; pf < 2; ++pf) {
      const int pix = pix0 + pf * 16 + col;
      short8 v;
      if (ks < 2) {
        v = *(const short8*)&vlds[pix * 72 + ks * 32 + kg * 8];
      } else {
        v = *(const short8*)(attn_nhwc + ((long)bh * WW + pix) * 64 +
                             (ks - 2) * 32 + kg * 8);
      }
      bfr[pf] = v;
    }
    #pragma unroll
    for (int mf = 0; mf < 4; ++mf) {
      const short8 afr =
          *(const short8*)(packedA + ((long)(ks * 4 + mf) * 64 + l) * 8);
      #pragma unroll
      for (int pf = 0; pf < 2; ++pf)
        ao[mf][pf] = __builtin_amdgcn_mfma_f32_16x16x32_bf16(
            afr, bfr[pf], ao[mf][pf], 0, 0, 0);
    }
  }

  // direct NCHW f32 stores
  #pragma unroll
  for (int mf = 0; mf < 4; ++mf)
    #pragma unroll
    for (int pf = 0; pf < 2; ++pf)
      #pragma unroll
      for (int r = 0; r < 4; ++r) {
        const int n = mf * 16 + kg * 4 + r;
        const int pix = pix0 + pf * 16 + col;
        float o = ao[mf][pf][r] + b_attn[n];
        o = (o >= 0.f) ? o : 0.2f * o;
        out[((long)(b * ENC_C + n) * HH + h) * WW + pix] = o;
      }
}

// ---------------------------------------------------------------------------
extern "C" void kernel_launch(void* const* d_in, const int* in_sizes, int n_in,
                              void* d_out, int out_size, void* d_ws, size_t ws_size,
                              hipStream_t stream) {
  const float* enc    = (const float*)d_in[0];
  const float* dec    = (const float*)d_in[1];
  const float* W_enc  = (const float*)d_in[2];
  const float* b_enc  = (const float*)d_in[3];
  const float* W_dec  = (const float*)d_in[4];
  const float* b_dec  = (const float*)d_in[5];
  const float* W_agg  = (const float*)d_in[6];
  const float* b_agg  = (const float*)d_in[7];
  const float* W_attn = (const float*)d_in[8];
  const float* b_attn = (const float*)d_in[9];
  const float* conv_w = (const float*)d_in[10];
  const float* conv_b = (const float*)d_in[11];
  float* out = (float*)d_out;

  const long npix = (long)BB * HH * WW;               // 131072
  ushort_t* q_bf    = (ushort_t*)d_ws;                // [npix][64] bf16 NHWC
  ushort_t* k_bf    = q_bf + npix * 64;               // [npix][64]
  ushort_t* enc_t   = k_bf + npix * 64;               // [npix][64]
  ushort_t* dec_t   = enc_t + npix * 64;              // [npix][128]
  ushort_t* att     = dec_t + npix * 128;             // [npix][64]
  ushort_t* packedC = att + npix * 64;                // conv W frags
  ushort_t* packedA = packedC + 144 * 64 * 8;
  ushort_t* packedQ = packedA + 16 * 64 * 8;
  ushort_t* packedK = packedQ + 16 * 64 * 8;

  hipLaunchKernelGGL(pack_w_kernel, dim3(184), dim3(64), 0, stream,
                     conv_w, W_attn, W_dec, W_enc, packedC, packedA, packedQ, packedK);
  hipLaunchKernelGGL(prep_kernel, dim3(BB * HH), dim3(256), 0, stream,
                     enc, dec, packedQ, packedK, b_enc, b_dec, q_bf, k_bf, enc_t, dec_t);
  hipLaunchKernelGGL(attn_kernel, dim3((int)(npix * 4 / 256)), dim3(256), 0, stream,
                     q_bf, k_bf, enc_t, W_agg, b_agg, att);
  hipLaunchKernelGGL(conv_out_kernel, dim3(BB * HH), dim3(256), 0, stream,
                     dec_t, packedC, conv_b, att, packedA, b_attn, out);
}

// Round 15
// 136.404 us; speedup vs baseline: 1.5657x; 1.5657x over previous
//
#include <hip/hip_runtime.h>

#define BB 8
#define ENC_C 64
#define DEC_C 128
#define HH 128
#define WW 128

typedef unsigned short ushort_t;
typedef __attribute__((ext_vector_type(8))) short short8;
typedef __attribute__((ext_vector_type(4))) short short4v;
typedef __attribute__((ext_vector_type(4))) float f32x4;

static __device__ __forceinline__ ushort_t f2bf(float x) {
  unsigned int u = __builtin_bit_cast(unsigned int, x);
  u += 0x7fff + ((u >> 16) & 1);   // round-to-nearest-even
  return (ushort_t)(u >> 16);
}
static __device__ __forceinline__ float bf2f(ushort_t v) {
  unsigned int u = ((unsigned int)v) << 16;
  return __builtin_bit_cast(float, u);
}

// ---------------------------------------------------------------------------
// Kernel 0: pack weight fragments (bf16).
//   blk 0..143   : COMPOSED conv weights W' = conv_w @ W1  -> packedC2
//                  (W1 = W_attn rows 0..63; layout [tap][ds][nf], 16KB/tap)
//   blk 144..151 : W2 = W_attn rows 64..127 (K=64)         -> packedW2
//   blk 152..167 : W_dec  (K=128)                           -> packedQ
//   blk 168..175 : W_enc  (K=64)                            -> packedK
//   blk 176      : bias_total = conv_b @ W1 + b_attn (f32)
// Frag: lane l, elem j holds W[k = ks*32 + (l>>4)*8 + j][n = nf*16 + (l&15)].
// ---------------------------------------------------------------------------
__global__ __launch_bounds__(64) void pack_w_kernel(
    const float* __restrict__ conv_w, const float* __restrict__ W_attn,
    const float* __restrict__ W_dec, const float* __restrict__ W_enc,
    const float* __restrict__ conv_b, const float* __restrict__ b_attn,
    ushort_t* __restrict__ packedC2, ushort_t* __restrict__ packedW2,
    ushort_t* __restrict__ packedQ, ushort_t* __restrict__ packedK,
    float* __restrict__ bias_total)
{
  const int blk = blockIdx.x;
  const int l = threadIdx.x;

  if (blk < 144) {
    // composed conv weights: W'[tap][d][n] = sum_c conv_w[tap][d][c]*W1[c][n]
    const int kstep = blk >> 2, nf = blk & 3;
    const int tap = kstep >> 2, dstep = kstep & 3;
    const int n = nf * 16 + (l & 15);
    const int dbase = dstep * 32 + (l >> 4) * 8;
    float wcol[64];
    #pragma unroll
    for (int c = 0; c < 64; ++c) wcol[c] = W_attn[c * 64 + n];
    ushort_t v[8];
    #pragma unroll
    for (int j = 0; j < 8; ++j) {
      const float* cw = conv_w + ((long)(tap * DEC_C + dbase + j)) * 64;
      float acc = 0.f;
      #pragma unroll
      for (int c = 0; c < 64; ++c) acc = __builtin_fmaf(cw[c], wcol[c], acc);
      v[j] = f2bf(acc);
    }
    ushort_t* d = packedC2 + (((long)tap * 16 + dstep * 4 + nf) * 64 + l) * 8;
    #pragma unroll
    for (int j = 0; j < 8; ++j) d[j] = v[j];
    return;
  }
  if (blk == 176) {
    float acc = b_attn[l];
    #pragma unroll
    for (int c = 0; c < 64; ++c)
      acc = __builtin_fmaf(conv_b[c], W_attn[c * 64 + l], acc);
    bias_total[l] = acc;
    return;
  }

  const float* W;
  ushort_t* dst;
  int bb, krow0;
  if (blk < 152)      { W = W_attn; dst = packedW2; bb = blk - 144; krow0 = 64; }
  else if (blk < 168) { W = W_dec;  dst = packedQ;  bb = blk - 152; krow0 = 0; }
  else                { W = W_enc;  dst = packedK;  bb = blk - 168; krow0 = 0; }
  const int ks = bb >> 2, nf = bb & 3;
  const int n = nf * 16 + (l & 15);
  const int kbase = krow0 + ks * 32 + (l >> 4) * 8;
  ushort_t v[8];
  #pragma unroll
  for (int j = 0; j < 8; ++j)
    v[j] = f2bf(W[(kbase + j) * 64 + n]);
  ushort_t* d = dst + ((long)bb * 64 + l) * 8;
  #pragma unroll
  for (int j = 0; j < 8; ++j) d[j] = v[j];
}

// ---------------------------------------------------------------------------
// Kernel 1: per (b,h) row. MFMA (A = pixel frags from LDS, B = packed W).
// Outputs q/k NHWC bf16 (+bias), encW = enc@W2 NHWC bf16, dec_t NHWC bf16.
// encW shares the afr frags with k (same enc tile). No waves-per-EU cap
// (R6: caps here spill to scratch).
// ---------------------------------------------------------------------------
__global__ __launch_bounds__(256) void prep_kernel(
    const float* __restrict__ enc, const float* __restrict__ dec,
    const ushort_t* __restrict__ packedQ, const ushort_t* __restrict__ packedK,
    const ushort_t* __restrict__ packedW2,
    const float* __restrict__ b_enc, const float* __restrict__ b_dec,
    ushort_t* __restrict__ q_nhwc, ushort_t* __restrict__ k_nhwc,
    ushort_t* __restrict__ encw, ushort_t* __restrict__ dec_t)
{
  __shared__ float smem[WW * 68];
  const int bh = blockIdx.x;
  const int b = bh >> 7, h = bh & 127;
  const int tid = threadIdx.x;
  const int l = tid & 63;
  const int wv = tid >> 6;
  const int pix0 = wv * 32;
  const int col = l & 15, kg = l >> 4;

  // ---- encoder tile [w][c] f32 ----
  #pragma unroll
  for (int i = 0; i < 32; ++i) {
    int idx = tid + i * 256;
    int cc = idx >> 7, wl = idx & 127;
    smem[wl * 68 + cc] = enc[((b * ENC_C + cc) * HH + h) * WW + wl];
  }
  __syncthreads();

  // k = enc @ W_enc + b ; encW = enc @ W2   (A = pixels -> D NHWC)
  f32x4 acck[2][4], accw[2][4];
  #pragma unroll
  for (int mf = 0; mf < 2; ++mf)
    #pragma unroll
    for (int nf = 0; nf < 4; ++nf) {
      acck[mf][nf] = (f32x4){0.f, 0.f, 0.f, 0.f};
      accw[mf][nf] = (f32x4){0.f, 0.f, 0.f, 0.f};
    }

  #pragma unroll
  for (int ks = 0; ks < 2; ++ks) {
    short8 afr[2];
    #pragma unroll
    for (int mf = 0; mf < 2; ++mf) {
      const int pix = pix0 + mf * 16 + col;
      const float4* p = (const float4*)&smem[pix * 68 + ks * 32 + kg * 8];
      float4 x0 = p[0], x1 = p[1];
      short8 v;
      v[0] = (short)f2bf(x0.x); v[1] = (short)f2bf(x0.y);
      v[2] = (short)f2bf(x0.z); v[3] = (short)f2bf(x0.w);
      v[4] = (short)f2bf(x1.x); v[5] = (short)f2bf(x1.y);
      v[6] = (short)f2bf(x1.z); v[7] = (short)f2bf(x1.w);
      afr[mf] = v;
    }
    #pragma unroll
    for (int nf = 0; nf < 4; ++nf) {
      const short8 bk =
          *(const short8*)(packedK + ((long)(ks * 4 + nf) * 64 + l) * 8);
      const short8 bw =
          *(const short8*)(packedW2 + ((long)(ks * 4 + nf) * 64 + l) * 8);
      #pragma unroll
      for (int mf = 0; mf < 2; ++mf) {
        acck[mf][nf] = __builtin_amdgcn_mfma_f32_16x16x32_bf16(
            afr[mf], bk, acck[mf][nf], 0, 0, 0);
        accw[mf][nf] = __builtin_amdgcn_mfma_f32_16x16x32_bf16(
            afr[mf], bw, accw[mf][nf], 0, 0, 0);
      }
    }
  }
  // store k and encW (NHWC bf16)
  #pragma unroll
  for (int mf = 0; mf < 2; ++mf)
    #pragma unroll
    for (int nf = 0; nf < 4; ++nf)
      #pragma unroll
      for (int r = 0; r < 4; ++r) {
        const int pix = pix0 + mf * 16 + kg * 4 + r;
        const int c = nf * 16 + col;
        k_nhwc[((long)bh * WW + pix) * 64 + c] = f2bf(acck[mf][nf][r] + b_enc[c]);
        encw[((long)bh * WW + pix) * 64 + c]   = f2bf(accw[mf][nf][r]);
      }
  __syncthreads();

  // ---- decoder tile, two 64-channel halves ----
  f32x4 accq[2][4];
  #pragma unroll
  for (int mf = 0; mf < 2; ++mf)
    #pragma unroll
    for (int nf = 0; nf < 4; ++nf)
      accq[mf][nf] = (f32x4){0.f, 0.f, 0.f, 0.f};

  #pragma unroll
  for (int hf = 0; hf < 2; ++hf) {
    #pragma unroll
    for (int i = 0; i < 32; ++i) {
      int idx = tid + i * 256;
      int cc = idx >> 7, wl = idx & 127;
      smem[wl * 68 + cc] = dec[((b * DEC_C + hf * 64 + cc) * HH + h) * WW + wl];
    }
    __syncthreads();

    // dec_t NHWC bf16
    #pragma unroll
    for (int i = 0; i < 32; ++i) {
      int idx = tid + i * 256;
      int wl = idx >> 6, cc = idx & 63;
      dec_t[((long)bh * WW + wl) * DEC_C + hf * 64 + cc] =
          f2bf(smem[wl * 68 + cc]);
    }

    #pragma unroll
    for (int ks2 = 0; ks2 < 2; ++ks2) {
      const int ks = hf * 2 + ks2;
      short8 afr[2];
      #pragma unroll
      for (int mf = 0; mf < 2; ++mf) {
        const int pix = pix0 + mf * 16 + col;
        const float4* p = (const float4*)&smem[pix * 68 + ks2 * 32 + kg * 8];
        float4 x0 = p[0], x1 = p[1];
        short8 v;
        v[0] = (short)f2bf(x0.x); v[1] = (short)f2bf(x0.y);
        v[2] = (short)f2bf(x0.z); v[3] = (short)f2bf(x0.w);
        v[4] = (short)f2bf(x1.x); v[5] = (short)f2bf(x1.y);
        v[6] = (short)f2bf(x1.z); v[7] = (short)f2bf(x1.w);
        afr[mf] = v;
      }
      #pragma unroll
      for (int nf = 0; nf < 4; ++nf) {
        const short8 bfr =
            *(const short8*)(packedQ + ((long)(ks * 4 + nf) * 64 + l) * 8);
        accq[0][nf] = __builtin_amdgcn_mfma_f32_16x16x32_bf16(
            afr[0], bfr, accq[0][nf], 0, 0, 0);
        accq[1][nf] = __builtin_amdgcn_mfma_f32_16x16x32_bf16(
            afr[1], bfr, accq[1][nf], 0, 0, 0);
      }
    }
    __syncthreads();
  }

  // store q NHWC bf16
  #pragma unroll
  for (int mf = 0; mf < 2; ++mf)
    #pragma unroll
    for (int nf = 0; nf < 4; ++nf)
      #pragma unroll
      for (int r = 0; r < 4; ++r) {
        const int pix = pix0 + mf * 16 + kg * 4 + r;
        const int c = nf * 16 + col;
        q_nhwc[((long)bh * WW + pix) * 64 + c] = f2bf(accq[mf][nf][r] + b_dec[c]);
      }
}

// ---------------------------------------------------------------------------
// Kernel 2: attention, FOUR threads per pixel (16 channels each).
// Weighted sum now over encW (= enc@W2) -> output attW2 = attn_vec @ W2.
// ---------------------------------------------------------------------------
__global__ __launch_bounds__(256) void attn_kernel(
    const ushort_t* __restrict__ q_nhwc, const ushort_t* __restrict__ k_nhwc,
    const ushort_t* __restrict__ encw, const float* __restrict__ W_agg,
    const float* __restrict__ b_agg, ushort_t* __restrict__ attw2)
{
  const int nwg = gridDim.x;                 // 2048, divisible by 8
  const int cpx = nwg >> 3;
  const int bid = blockIdx.x;
  const int swz = (bid & 7) * cpx + (bid >> 3);   // XCD-contiguous pixels
  const int t = swz * 256 + threadIdx.x;     // 0 .. 4*npix-1
  const int pix = t >> 2;
  const int cb = (t & 3) * 16;               // this thread's channel base
  const int h = (pix >> 7) & 127;
  const int w = pix & 127;

  int off[9]; bool valid[9];
  #pragma unroll
  for (int n = 0; n < 9; ++n) {
    const int dh = n / 3 - 1, dw = n % 3 - 1;
    const int nh = h + dh, nw = w + dw;
    valid[n] = (nh >= 0 && nh < HH && nw >= 0 && nw < WW);
    const int nhc = min(max(nh, 0), HH - 1);
    const int nwc = min(max(nw, 0), WW - 1);
    off[n] = (pix & ~16383) + nhc * WW + nwc;  // same batch, clamped pixel
  }

  const short8* qp = (const short8*)(q_nhwc + ((long)pix << 6) + cb);
  const short8 qa = qp[0], qb = qp[1];

  float wa[16];
  {
    float4 w0 = *(const float4*)(W_agg + cb);
    float4 w1 = *(const float4*)(W_agg + cb + 4);
    float4 w2 = *(const float4*)(W_agg + cb + 8);
    float4 w3 = *(const float4*)(W_agg + cb + 12);
    wa[0]=w0.x; wa[1]=w0.y; wa[2]=w0.z; wa[3]=w0.w;
    wa[4]=w1.x; wa[5]=w1.y; wa[6]=w1.z; wa[7]=w1.w;
    wa[8]=w2.x; wa[9]=w2.y; wa[10]=w2.z; wa[11]=w2.w;
    wa[12]=w3.x; wa[13]=w3.y; wa[14]=w3.z; wa[15]=w3.w;
  }

  // ---- score partials over this thread's 16 channels ----
  float s[9];
  #pragma unroll
  for (int n = 0; n < 9; ++n) {
    const short8* kp = (const short8*)(k_nhwc + ((long)off[n] << 6) + cb);
    const short8 ka = kp[0], kb = kp[1];
    float sc = 0.f;
    #pragma unroll
    for (int e = 0; e < 8; ++e) {
      float x = bf2f((ushort_t)qa[e]) + bf2f((ushort_t)ka[e]);
      x = fminf(fmaxf(x, -15.f), 15.f);
      float z = __builtin_amdgcn_exp2f(x * 2.88539008f);
      float tt = __builtin_fmaf(-2.f, __builtin_amdgcn_rcpf(z + 1.f), 1.f);
      sc = __builtin_fmaf(tt, wa[e], sc);
    }
    #pragma unroll
    for (int e = 0; e < 8; ++e) {
      float x = bf2f((ushort_t)qb[e]) + bf2f((ushort_t)kb[e]);
      x = fminf(fmaxf(x, -15.f), 15.f);
      float z = __builtin_amdgcn_exp2f(x * 2.88539008f);
      float tt = __builtin_fmaf(-2.f, __builtin_amdgcn_rcpf(z + 1.f), 1.f);
      sc = __builtin_fmaf(tt, wa[8 + e], sc);
    }
    s[n] = sc;
  }

  // ---- combine partials across the 4 lanes of this pixel ----
  #pragma unroll
  for (int n = 0; n < 9; ++n) {
    s[n] += __shfl_xor(s[n], 1);
    s[n] += __shfl_xor(s[n], 2);
  }

  // ---- masked softmax (duplicated in all 4 lanes) ----
  const float bagg = b_agg[0];
  float m = -1e30f;
  #pragma unroll
  for (int n = 0; n < 9; ++n) {
    s[n] = valid[n] ? (s[n] + bagg) : -1e30f;
    m = fmaxf(m, s[n]);
  }
  float attw[9]; float denom = 0.f;
  #pragma unroll
  for (int n = 0; n < 9; ++n) {
    attw[n] = __builtin_amdgcn_exp2f((s[n] - m) * 1.44269504f);
    denom += attw[n];
  }
  const float inv = __builtin_amdgcn_rcpf(denom);
  #pragma unroll
  for (int n = 0; n < 9; ++n) attw[n] *= inv;   // invalid -> exactly 0

  // ---- weighted encW sum over this thread's 16 channels ----
  float a16[16];
  #pragma unroll
  for (int e = 0; e < 16; ++e) a16[e] = 0.f;
  #pragma unroll
  for (int n = 0; n < 9; ++n) {
    const short8* ep = (const short8*)(encw + ((long)off[n] << 6) + cb);
    const short8 ea = ep[0], eb = ep[1];
    #pragma unroll
    for (int e = 0; e < 8; ++e)
      a16[e] = __builtin_fmaf(attw[n], bf2f((ushort_t)ea[e]), a16[e]);
    #pragma unroll
    for (int e = 0; e < 8; ++e)
      a16[8 + e] = __builtin_fmaf(attw[n], bf2f((ushort_t)eb[e]), a16[8 + e]);
  }
  short8 o0, o1;
  #pragma unroll
  for (int e = 0; e < 8; ++e) {
    o0[e] = (short)f2bf(a16[e]);
    o1[e] = (short)f2bf(a16[8 + e]);
  }
  short8* op = (short8*)(attw2 + ((long)pix << 6) + cb);
  op[0] = o0;
  op[1] = o1;
}

// ---------------------------------------------------------------------------
// Kernel 3: conv with COMPOSED weights, swapped MFMA (A = W' frags from
// staged LDS, B = pixel frags from global) -> D = (ch, pix). One row/block
// (grid 1024), 9-phase dbuf async staging (R11 structure). Epilogue:
// out = LeakyReLU(acc + attW2 + bias_total), direct coalesced NCHW store.
// No out-phase, no vals LDS bounce; LDS 32 KB.
// ---------------------------------------------------------------------------
__global__ __launch_bounds__(256) void conv2_kernel(
    const ushort_t* __restrict__ dec_t, const ushort_t* __restrict__ packedC2,
    const ushort_t* __restrict__ attw2, const float* __restrict__ bias_total,
    float* __restrict__ out)
{
  __shared__ ushort_t bsh[16384];            // 32 KB: 2 x 16KB tap buffers
  const int nwg = gridDim.x;                 // 1024, divisible by 8
  const int cpx = nwg >> 3;
  const int bid = blockIdx.x;
  const int bh = (bid & 7) * cpx + (bid >> 3);
  const int b = bh >> 7, h = bh & 127;
  const int tid = threadIdx.x;
  const int l = tid & 63;
  const int wv = tid >> 6;
  const int pix0 = wv * 32;
  const int col = l & 15, kg = l >> 4;

  // async-stage tap slice (16 frags = 16KB) into buf[tap&1]
  auto stage = [&](int tap) {
    const ushort_t* src = packedC2 + (long)tap * 8192;
    ushort_t* dstb = bsh + (tap & 1) * 8192 + (long)(tid & ~63) * 8;
    #pragma unroll
    for (int i = 0; i < 4; ++i) {
      __builtin_amdgcn_global_load_lds(
          (const __attribute__((address_space(1))) void*)(src + (long)(i * 256 + tid) * 8),
          (__attribute__((address_space(3))) void*)(dstb + i * 256 * 8),
          16, 0, 0);
    }
  };

  f32x4 acc[4][2];                           // [ch frag mf][pix frag pf]
  #pragma unroll
  for (int mf = 0; mf < 4; ++mf)
    #pragma unroll
    for (int pf = 0; pf < 2; ++pf)
      acc[mf][pf] = (f32x4){0.f, 0.f, 0.f, 0.f};

  stage(0);

  #pragma unroll
  for (int p = 0; p < 9; ++p) {
    __syncthreads();                         // buf[p&1] staged; prior reads done
    if (p + 1 < 9) stage(p + 1);             // async loads fly across compute
    const int kh = p / 3, kw = p % 3;
    const int hh = h + kh - 1;
    if (hh >= 0 && hh < HH) {                // block-uniform skip
      const ushort_t* arow = dec_t + ((long)(b * HH + hh) * WW) * DEC_C;
      const ushort_t* bbase = bsh + (p & 1) * 8192;
      // B-frags: pixel data (col = pixel, k = dec ch)
      short8 pfr[4][2];
      #pragma unroll
      for (int pf = 0; pf < 2; ++pf) {
        const int wp = pix0 + pf * 16 + col + kw - 1;
        const bool ok = (wp >= 0 && wp < WW);
        #pragma unroll
        for (int ds = 0; ds < 4; ++ds) {
          short8 z = {0, 0, 0, 0, 0, 0, 0, 0};
          pfr[ds][pf] = ok
              ? *(const short8*)(arow + (long)wp * DEC_C + ds * 32 + kg * 8) : z;
        }
      }
      #pragma unroll
      for (int ds = 0; ds < 4; ++ds)
        #pragma unroll
        for (int mf = 0; mf < 4; ++mf) {
          const short8 wfr =
              *(const short8*)(bbase + ((ds * 4 + mf) * 64 + l) * 8);
          acc[mf][0] = __builtin_amdgcn_mfma_f32_16x16x32_bf16(
              wfr, pfr[ds][0], acc[mf][0], 0, 0, 0);
          acc[mf][1] = __builtin_amdgcn_mfma_f32_16x16x32_bf16(
              wfr, pfr[ds][1], acc[mf][1], 0, 0, 0);
        }
    }
  }

  // ---- epilogue: + attW2 + bias_total, LeakyReLU, NCHW store ----
  #pragma unroll
  for (int mf = 0; mf < 4; ++mf)
    #pragma unroll
    for (int pf = 0; pf < 2; ++pf) {
      const int pix = pix0 + pf * 16 + col;
      const short4v av = *(const short4v*)(
          attw2 + ((long)bh * WW + pix) * 64 + mf * 16 + kg * 4);
      #pragma unroll
      for (int r = 0; r < 4; ++r) {
        const int ch = mf * 16 + kg * 4 + r;
        float o = acc[mf][pf][r] + bf2f((ushort_t)av[r]) + bias_total[ch];
        o = (o >= 0.f) ? o : 0.2f * o;
        out[((long)(b * ENC_C + ch) * HH + h) * WW + pix] = o;
      }
    }
}

// ---------------------------------------------------------------------------
extern "C" void kernel_launch(void* const* d_in, const int* in_sizes, int n_in,
                              void* d_out, int out_size, void* d_ws, size_t ws_size,
                              hipStream_t stream) {
  const float* enc    = (const float*)d_in[0];
  const float* dec    = (const float*)d_in[1];
  const float* W_enc  = (const float*)d_in[2];
  const float* b_enc  = (const float*)d_in[3];
  const float* W_dec  = (const float*)d_in[4];
  const float* b_dec  = (const float*)d_in[5];
  const float* W_agg  = (const float*)d_in[6];
  const float* b_agg  = (const float*)d_in[7];
  const float* W_attn = (const float*)d_in[8];
  const float* b_attn = (const float*)d_in[9];
  const float* conv_w = (const float*)d_in[10];
  const float* conv_b = (const float*)d_in[11];
  float* out = (float*)d_out;

  const long npix = (long)BB * HH * WW;               // 131072
  ushort_t* q_bf     = (ushort_t*)d_ws;               // [npix][64] bf16 NHWC
  ushort_t* k_bf     = q_bf + npix * 64;              // [npix][64]
  ushort_t* encw     = k_bf + npix * 64;              // [npix][64]  enc@W2
  ushort_t* dec_t    = encw + npix * 64;              // [npix][128]
  ushort_t* attw2    = dec_t + npix * 128;            // [npix][64]  attn@W2
  ushort_t* packedC2 = attw2 + npix * 64;             // composed conv W frags
  ushort_t* packedW2 = packedC2 + 144 * 64 * 8;       // W2 frags (8 blocks)
  ushort_t* packedQ  = packedW2 + 8 * 64 * 8;         // W_dec frags (16)
  ushort_t* packedK  = packedQ + 16 * 64 * 8;         // W_enc frags (8)
  float* bias_total  = (float*)(packedK + 8 * 64 * 8);// [64] f32

  hipLaunchKernelGGL(pack_w_kernel, dim3(177), dim3(64), 0, stream,
                     conv_w, W_attn, W_dec, W_enc, conv_b, b_attn,
                     packedC2, packedW2, packedQ, packedK, bias_total);
  hipLaunchKernelGGL(prep_kernel, dim3(BB * HH), dim3(256), 0, stream,
                     enc, dec, packedQ, packedK, packedW2, b_enc, b_dec,
                     q_bf, k_bf, encw, dec_t);
  hipLaunchKernelGGL(attn_kernel, dim3((int)(npix * 4 / 256)), dim3(256), 0, stream,
                     q_bf, k_bf, encw, W_agg, b_agg, attw2);
  hipLaunchKernelGGL(conv2_kernel, dim3(BB * HH), dim3(256), 0, stream,
                     dec_t, packedC2, attw2, bias_total, out);
}

// Round 16
// 136.011 us; speedup vs baseline: 1.5703x; 1.0029x over previous
//
#include <hip/hip_runtime.h>

#define BB 8
#define ENC_C 64
#define DEC_C 128
#define HH 128
#define WW 128

typedef unsigned short ushort_t;
typedef __attribute__((ext_vector_type(8))) short short8;
typedef __attribute__((ext_vector_type(4))) short short4v;
typedef __attribute__((ext_vector_type(4))) float f32x4;

static __device__ __forceinline__ ushort_t f2bf(float x) {
  unsigned int u = __builtin_bit_cast(unsigned int, x);
  u += 0x7fff + ((u >> 16) & 1);   // round-to-nearest-even
  return (ushort_t)(u >> 16);
}
static __device__ __forceinline__ float bf2f(ushort_t v) {
  unsigned int u = ((unsigned int)v) << 16;
  return __builtin_bit_cast(float, u);
}

// ---------------------------------------------------------------------------
// Kernel 0: pack weight fragments (bf16).
//   blk 0..143   : COMPOSED conv weights W' = conv_w @ W1  -> packedC2
//   blk 144..151 : W2 = W_attn rows 64..127 (K=64)         -> packedW2
//   blk 152..167 : W_dec  (K=128)                           -> packedQ
//   blk 168..175 : W_enc  (K=64)                            -> packedK
//   blk 176      : bias_total = conv_b @ W1 + b_attn (f32)
// Frag: lane l, elem j holds W[k = ks*32 + (l>>4)*8 + j][n = nf*16 + (l&15)].
// ---------------------------------------------------------------------------
__global__ __launch_bounds__(64) void pack_w_kernel(
    const float* __restrict__ conv_w, const float* __restrict__ W_attn,
    const float* __restrict__ W_dec, const float* __restrict__ W_enc,
    const float* __restrict__ conv_b, const float* __restrict__ b_attn,
    ushort_t* __restrict__ packedC2, ushort_t* __restrict__ packedW2,
    ushort_t* __restrict__ packedQ, ushort_t* __restrict__ packedK,
    float* __restrict__ bias_total)
{
  const int blk = blockIdx.x;
  const int l = threadIdx.x;

  if (blk < 144) {
    const int kstep = blk >> 2, nf = blk & 3;
    const int tap = kstep >> 2, dstep = kstep & 3;
    const int n = nf * 16 + (l & 15);
    const int dbase = dstep * 32 + (l >> 4) * 8;
    float wcol[64];
    #pragma unroll
    for (int c = 0; c < 64; ++c) wcol[c] = W_attn[c * 64 + n];
    ushort_t v[8];
    #pragma unroll
    for (int j = 0; j < 8; ++j) {
      const float* cw = conv_w + ((long)(tap * DEC_C + dbase + j)) * 64;
      float acc = 0.f;
      #pragma unroll
      for (int c = 0; c < 64; ++c) acc = __builtin_fmaf(cw[c], wcol[c], acc);
      v[j] = f2bf(acc);
    }
    ushort_t* d = packedC2 + (((long)tap * 16 + dstep * 4 + nf) * 64 + l) * 8;
    #pragma unroll
    for (int j = 0; j < 8; ++j) d[j] = v[j];
    return;
  }
  if (blk == 176) {
    float acc = b_attn[l];
    #pragma unroll
    for (int c = 0; c < 64; ++c)
      acc = __builtin_fmaf(conv_b[c], W_attn[c * 64 + l], acc);
    bias_total[l] = acc;
    return;
  }

  const float* W;
  ushort_t* dst;
  int bb, krow0;
  if (blk < 152)      { W = W_attn; dst = packedW2; bb = blk - 144; krow0 = 64; }
  else if (blk < 168) { W = W_dec;  dst = packedQ;  bb = blk - 152; krow0 = 0; }
  else                { W = W_enc;  dst = packedK;  bb = blk - 168; krow0 = 0; }
  const int ks = bb >> 2, nf = bb & 3;
  const int n = nf * 16 + (l & 15);
  const int kbase = krow0 + ks * 32 + (l >> 4) * 8;
  ushort_t v[8];
  #pragma unroll
  for (int j = 0; j < 8; ++j)
    v[j] = f2bf(W[(kbase + j) * 64 + n]);
  ushort_t* d = dst + ((long)bb * 64 + l) * 8;
  #pragma unroll
  for (int j = 0; j < 8; ++j) d[j] = v[j];
}

// ---------------------------------------------------------------------------
// Kernel 1: per (b,h) row.
// enc phase: A-frags DIRECT from global NCHW (no LDS, no barriers) -> k, encW.
// dec phase: 4-plane float4 LDS writes (b128 = LDS structural floor, no
// conflict penalty), b128 row reads -> short4 dec_t stores; q MFMA from LDS.
// No waves-per-EU cap (R6: caps here spill to scratch).
// ---------------------------------------------------------------------------
__global__ __launch_bounds__(256) void prep_kernel(
    const float* __restrict__ enc, const float* __restrict__ dec,
    const ushort_t* __restrict__ packedQ, const ushort_t* __restrict__ packedK,
    const ushort_t* __restrict__ packedW2,
    const float* __restrict__ b_enc, const float* __restrict__ b_dec,
    ushort_t* __restrict__ q_nhwc, ushort_t* __restrict__ k_nhwc,
    ushort_t* __restrict__ encw, ushort_t* __restrict__ dec_t)
{
  __shared__ float smem[WW * 68];
  const int bh = blockIdx.x;
  const int b = bh >> 7, h = bh & 127;
  const int tid = threadIdx.x;
  const int l = tid & 63;
  const int wv = tid >> 6;
  const int pix0 = wv * 32;
  const int col = l & 15, kg = l >> 4;
  const long plane = (long)HH * WW;

  // ================= enc phase: k = enc@W_enc + b, encW = enc@W2 ==========
  {
    const float* ebase = enc + ((long)(b * ENC_C) * HH + h) * WW;
    f32x4 acck[2][4], accw[2][4];
    #pragma unroll
    for (int mf = 0; mf < 2; ++mf)
      #pragma unroll
      for (int nf = 0; nf < 4; ++nf) {
        acck[mf][nf] = (f32x4){0.f, 0.f, 0.f, 0.f};
        accw[mf][nf] = (f32x4){0.f, 0.f, 0.f, 0.f};
      }

    #pragma unroll
    for (int ks = 0; ks < 2; ++ks) {
      short8 afr[2];
      #pragma unroll
      for (int mf = 0; mf < 2; ++mf) {
        const int pix = pix0 + mf * 16 + col;
        const float* p = ebase + (long)(ks * 32 + kg * 8) * plane + pix;
        short8 v;
        #pragma unroll
        for (int j = 0; j < 8; ++j) v[j] = (short)f2bf(p[(long)j * plane]);
        afr[mf] = v;
      }
      #pragma unroll
      for (int nf = 0; nf < 4; ++nf) {
        const short8 bk =
            *(const short8*)(packedK + ((long)(ks * 4 + nf) * 64 + l) * 8);
        const short8 bw =
            *(const short8*)(packedW2 + ((long)(ks * 4 + nf) * 64 + l) * 8);
        #pragma unroll
        for (int mf = 0; mf < 2; ++mf) {
          acck[mf][nf] = __builtin_amdgcn_mfma_f32_16x16x32_bf16(
              afr[mf], bk, acck[mf][nf], 0, 0, 0);
          accw[mf][nf] = __builtin_amdgcn_mfma_f32_16x16x32_bf16(
              afr[mf], bw, accw[mf][nf], 0, 0, 0);
        }
      }
    }
    // store k and encW (NHWC bf16)
    #pragma unroll
    for (int mf = 0; mf < 2; ++mf)
      #pragma unroll
      for (int nf = 0; nf < 4; ++nf)
        #pragma unroll
        for (int r = 0; r < 4; ++r) {
          const int pix = pix0 + mf * 16 + kg * 4 + r;
          const int c = nf * 16 + col;
          k_nhwc[((long)bh * WW + pix) * 64 + c] =
              f2bf(acck[mf][nf][r] + b_enc[c]);
          encw[((long)bh * WW + pix) * 64 + c] = f2bf(accw[mf][nf][r]);
        }
  }

  // ================= dec phase: dec_t + q =================================
  f32x4 accq[2][4];
  #pragma unroll
  for (int mf = 0; mf < 2; ++mf)
    #pragma unroll
    for (int nf = 0; nf < 4; ++nf)
      accq[mf][nf] = (f32x4){0.f, 0.f, 0.f, 0.f};

  #pragma unroll
  for (int hf = 0; hf < 2; ++hf) {
    // tile load: 4 c-planes per thread -> one float4 LDS write
    {
      const int w = tid & 127;
      const int cq = tid >> 7;               // 0/1
      const float* dbase =
          dec + ((long)(b * DEC_C + hf * 64) * HH + h) * WW + w;
      #pragma unroll
      for (int i = 0; i < 8; ++i) {
        const int cb4 = (i * 2 + cq) * 4;    // 0..60
        float4 v;
        v.x = dbase[(long)(cb4 + 0) * plane];
        v.y = dbase[(long)(cb4 + 1) * plane];
        v.z = dbase[(long)(cb4 + 2) * plane];
        v.w = dbase[(long)(cb4 + 3) * plane];
        *(float4*)&smem[w * 68 + cb4] = v;
      }
    }
    __syncthreads();

    // dec_t NHWC bf16: b128 LDS row reads -> short4 stores
    #pragma unroll
    for (int i = 0; i < 8; ++i) {
      const int idx = tid + i * 256;
      const int wl = idx >> 4;               // 0..127 over 8 iters
      const int cq4 = (idx & 15) * 4;        // 0..60
      const float4 v = *(const float4*)&smem[wl * 68 + cq4];
      short4v s;
      s[0] = (short)f2bf(v.x); s[1] = (short)f2bf(v.y);
      s[2] = (short)f2bf(v.z); s[3] = (short)f2bf(v.w);
      *(short4v*)(dec_t + ((long)bh * WW + wl) * DEC_C + hf * 64 + cq4) = s;
    }

    // q MFMA from LDS (float4 frag reads)
    #pragma unroll
    for (int ks2 = 0; ks2 < 2; ++ks2) {
      const int ks = hf * 2 + ks2;
      short8 afr[2];
      #pragma unroll
      for (int mf = 0; mf < 2; ++mf) {
        const int pix = pix0 + mf * 16 + col;
        const float4* p = (const float4*)&smem[pix * 68 + ks2 * 32 + kg * 8];
        float4 x0 = p[0], x1 = p[1];
        short8 v;
        v[0] = (short)f2bf(x0.x); v[1] = (short)f2bf(x0.y);
        v[2] = (short)f2bf(x0.z); v[3] = (short)f2bf(x0.w);
        v[4] = (short)f2bf(x1.x); v[5] = (short)f2bf(x1.y);
        v[6] = (short)f2bf(x1.z); v[7] = (short)f2bf(x1.w);
        afr[mf] = v;
      }
      #pragma unroll
      for (int nf = 0; nf < 4; ++nf) {
        const short8 bfr =
            *(const short8*)(packedQ + ((long)(ks * 4 + nf) * 64 + l) * 8);
        accq[0][nf] = __builtin_amdgcn_mfma_f32_16x16x32_bf16(
            afr[0], bfr, accq[0][nf], 0, 0, 0);
        accq[1][nf] = __builtin_amdgcn_mfma_f32_16x16x32_bf16(
            afr[1], bfr, accq[1][nf], 0, 0, 0);
      }
    }
    __syncthreads();
  }

  // store q NHWC bf16
  #pragma unroll
  for (int mf = 0; mf < 2; ++mf)
    #pragma unroll
    for (int nf = 0; nf < 4; ++nf)
      #pragma unroll
      for (int r = 0; r < 4; ++r) {
        const int pix = pix0 + mf * 16 + kg * 4 + r;
        const int c = nf * 16 + col;
        q_nhwc[((long)bh * WW + pix) * 64 + c] = f2bf(accq[mf][nf][r] + b_dec[c]);
      }
}

// ---------------------------------------------------------------------------
// Kernel 2: attention, FOUR threads per pixel (16 channels each).
// Weighted sum over encW (= enc@W2) -> output attW2 = attn_vec @ W2.
// ---------------------------------------------------------------------------
__global__ __launch_bounds__(256) void attn_kernel(
    const ushort_t* __restrict__ q_nhwc, const ushort_t* __restrict__ k_nhwc,
    const ushort_t* __restrict__ encw, const float* __restrict__ W_agg,
    const float* __restrict__ b_agg, ushort_t* __restrict__ attw2)
{
  const int nwg = gridDim.x;                 // 2048, divisible by 8
  const int cpx = nwg >> 3;
  const int bid = blockIdx.x;
  const int swz = (bid & 7) * cpx + (bid >> 3);   // XCD-contiguous pixels
  const int t = swz * 256 + threadIdx.x;     // 0 .. 4*npix-1
  const int pix = t >> 2;
  const int cb = (t & 3) * 16;               // this thread's channel base
  const int h = (pix >> 7) & 127;
  const int w = pix & 127;

  int off[9]; bool valid[9];
  #pragma unroll
  for (int n = 0; n < 9; ++n) {
    const int dh = n / 3 - 1, dw = n % 3 - 1;
    const int nh = h + dh, nw = w + dw;
    valid[n] = (nh >= 0 && nh < HH && nw >= 0 && nw < WW);
    const int nhc = min(max(nh, 0), HH - 1);
    const int nwc = min(max(nw, 0), WW - 1);
    off[n] = (pix & ~16383) + nhc * WW + nwc;  // same batch, clamped pixel
  }

  const short8* qp = (const short8*)(q_nhwc + ((long)pix << 6) + cb);
  const short8 qa = qp[0], qb = qp[1];

  float wa[16];
  {
    float4 w0 = *(const float4*)(W_agg + cb);
    float4 w1 = *(const float4*)(W_agg + cb + 4);
    float4 w2 = *(const float4*)(W_agg + cb + 8);
    float4 w3 = *(const float4*)(W_agg + cb + 12);
    wa[0]=w0.x; wa[1]=w0.y; wa[2]=w0.z; wa[3]=w0.w;
    wa[4]=w1.x; wa[5]=w1.y; wa[6]=w1.z; wa[7]=w1.w;
    wa[8]=w2.x; wa[9]=w2.y; wa[10]=w2.z; wa[11]=w2.w;
    wa[12]=w3.x; wa[13]=w3.y; wa[14]=w3.z; wa[15]=w3.w;
  }

  // ---- score partials over this thread's 16 channels ----
  float s[9];
  #pragma unroll
  for (int n = 0; n < 9; ++n) {
    const short8* kp = (const short8*)(k_nhwc + ((long)off[n] << 6) + cb);
    const short8 ka = kp[0], kb = kp[1];
    float sc = 0.f;
    #pragma unroll
    for (int e = 0; e < 8; ++e) {
      float x = bf2f((ushort_t)qa[e]) + bf2f((ushort_t)ka[e]);
      x = fminf(fmaxf(x, -15.f), 15.f);
      float z = __builtin_amdgcn_exp2f(x * 2.88539008f);
      float tt = __builtin_fmaf(-2.f, __builtin_amdgcn_rcpf(z + 1.f), 1.f);
      sc = __builtin_fmaf(tt, wa[e], sc);
    }
    #pragma unroll
    for (int e = 0; e < 8; ++e) {
      float x = bf2f((ushort_t)qb[e]) + bf2f((ushort_t)kb[e]);
      x = fminf(fmaxf(x, -15.f), 15.f);
      float z = __builtin_amdgcn_exp2f(x * 2.88539008f);
      float tt = __builtin_fmaf(-2.f, __builtin_amdgcn_rcpf(z + 1.f), 1.f);
      sc = __builtin_fmaf(tt, wa[8 + e], sc);
    }
    s[n] = sc;
  }

  // ---- combine partials across the 4 lanes of this pixel ----
  #pragma unroll
  for (int n = 0; n < 9; ++n) {
    s[n] += __shfl_xor(s[n], 1);
    s[n] += __shfl_xor(s[n], 2);
  }

  // ---- masked softmax (duplicated in all 4 lanes) ----
  const float bagg = b_agg[0];
  float m = -1e30f;
  #pragma unroll
  for (int n = 0; n < 9; ++n) {
    s[n] = valid[n] ? (s[n] + bagg) : -1e30f;
    m = fmaxf(m, s[n]);
  }
  float attw[9]; float denom = 0.f;
  #pragma unroll
  for (int n = 0; n < 9; ++n) {
    attw[n] = __builtin_amdgcn_exp2f((s[n] - m) * 1.44269504f);
    denom += attw[n];
  }
  const float inv = __builtin_amdgcn_rcpf(denom);
  #pragma unroll
  for (int n = 0; n < 9; ++n) attw[n] *= inv;   // invalid -> exactly 0

  // ---- weighted encW sum over this thread's 16 channels ----
  float a16[16];
  #pragma unroll
  for (int e = 0; e < 16; ++e) a16[e] = 0.f;
  #pragma unroll
  for (int n = 0; n < 9; ++n) {
    const short8* ep = (const short8*)(encw + ((long)off[n] << 6) + cb);
    const short8 ea = ep[0], eb = ep[1];
    #pragma unroll
    for (int e = 0; e < 8; ++e)
      a16[e] = __builtin_fmaf(attw[n], bf2f((ushort_t)ea[e]), a16[e]);
    #pragma unroll
    for (int e = 0; e < 8; ++e)
      a16[8 + e] = __builtin_fmaf(attw[n], bf2f((ushort_t)eb[e]), a16[8 + e]);
  }
  short8 o0, o1;
  #pragma unroll
  for (int e = 0; e < 8; ++e) {
    o0[e] = (short)f2bf(a16[e]);
    o1[e] = (short)f2bf(a16[8 + e]);
  }
  short8* op = (short8*)(attw2 + ((long)pix << 6) + cb);
  op[0] = o0;
  op[1] = o1;
}

// ---------------------------------------------------------------------------
// Kernel 3: conv with COMPOSED weights, swapped MFMA (A = W' frags from
// staged LDS, B = pixel frags from global) -> D = (ch, pix). One row/block
// (grid 1024), 9-phase dbuf async staging. Epilogue: + attW2 + bias_total,
// LeakyReLU, direct coalesced NCHW store. LDS 32 KB.
// ---------------------------------------------------------------------------
__global__ __launch_bounds__(256) void conv2_kernel(
    const ushort_t* __restrict__ dec_t, const ushort_t* __restrict__ packedC2,
    const ushort_t* __restrict__ attw2, const float* __restrict__ bias_total,
    float* __restrict__ out)
{
  __shared__ ushort_t bsh[16384];            // 32 KB: 2 x 16KB tap buffers
  const int nwg = gridDim.x;                 // 1024, divisible by 8
  const int cpx = nwg >> 3;
  const int bid = blockIdx.x;
  const int bh = (bid & 7) * cpx + (bid >> 3);
  const int b = bh >> 7, h = bh & 127;
  const int tid = threadIdx.x;
  const int l = tid & 63;
  const int wv = tid >> 6;
  const int pix0 = wv * 32;
  const int col = l & 15, kg = l >> 4;

  auto stage = [&](int tap) {
    const ushort_t* src = packedC2 + (long)tap * 8192;
    ushort_t* dstb = bsh + (tap & 1) * 8192 + (long)(tid & ~63) * 8;
    #pragma unroll
    for (int i = 0; i < 4; ++i) {
      __builtin_amdgcn_global_load_lds(
          (const __attribute__((address_space(1))) void*)(src + (long)(i * 256 + tid) * 8),
          (__attribute__((address_space(3))) void*)(dstb + i * 256 * 8),
          16, 0, 0);
    }
  };

  f32x4 acc[4][2];                           // [ch frag mf][pix frag pf]
  #pragma unroll
  for (int mf = 0; mf < 4; ++mf)
    #pragma unroll
    for (int pf = 0; pf < 2; ++pf)
      acc[mf][pf] = (f32x4){0.f, 0.f, 0.f, 0.f};

  stage(0);

  #pragma unroll
  for (int p = 0; p < 9; ++p) {
    __syncthreads();                         // buf[p&1] staged; prior reads done
    if (p + 1 < 9) stage(p + 1);             // async loads fly across compute
    const int kh = p / 3, kw = p % 3;
    const int hh = h + kh - 1;
    if (hh >= 0 && hh < HH) {                // block-uniform skip
      const ushort_t* arow = dec_t + ((long)(b * HH + hh) * WW) * DEC_C;
      const ushort_t* bbase = bsh + (p & 1) * 8192;
      short8 pfr[4][2];
      #pragma unroll
      for (int pf = 0; pf < 2; ++pf) {
        const int wp = pix0 + pf * 16 + col + kw - 1;
        const bool ok = (wp >= 0 && wp < WW);
        #pragma unroll
        for (int ds = 0; ds < 4; ++ds) {
          short8 z = {0, 0, 0, 0, 0, 0, 0, 0};
          pfr[ds][pf] = ok
              ? *(const short8*)(arow + (long)wp * DEC_C + ds * 32 + kg * 8) : z;
        }
      }
      #pragma unroll
      for (int ds = 0; ds < 4; ++ds)
        #pragma unroll
        for (int mf = 0; mf < 4; ++mf) {
          const short8 wfr =
              *(const short8*)(bbase + ((ds * 4 + mf) * 64 + l) * 8);
          acc[mf][0] = __builtin_amdgcn_mfma_f32_16x16x32_bf16(
              wfr, pfr[ds][0], acc[mf][0], 0, 0, 0);
          acc[mf][1] = __builtin_amdgcn_mfma_f32_16x16x32_bf16(
              wfr, pfr[ds][1], acc[mf][1], 0, 0, 0);
        }
    }
  }

  // ---- epilogue: + attW2 + bias_total, LeakyReLU, NCHW store ----
  #pragma unroll
  for (int mf = 0; mf < 4; ++mf)
    #pragma unroll
    for (int pf = 0; pf < 2; ++pf) {
      const int pix = pix0 + pf * 16 + col;
      const short4v av = *(const short4v*)(
          attw2 + ((long)bh * WW + pix) * 64 + mf * 16 + kg * 4);
      #pragma unroll
      for (int r = 0; r < 4; ++r) {
        const int ch = mf * 16 + kg * 4 + r;
        float o = acc[mf][pf][r] + bf2f((ushort_t)av[r]) + bias_total[ch];
        o = (o >= 0.f) ? o : 0.2f * o;
        out[((long)(b * ENC_C + ch) * HH + h) * WW + pix] = o;
      }
    }
}

// ---------------------------------------------------------------------------
extern "C" void kernel_launch(void* const* d_in, const int* in_sizes, int n_in,
                              void* d_out, int out_size, void* d_ws, size_t ws_size,
                              hipStream_t stream) {
  const float* enc    = (const float*)d_in[0];
  const float* dec    = (const float*)d_in[1];
  const float* W_enc  = (const float*)d_in[2];
  const float* b_enc  = (const float*)d_in[3];
  const float* W_dec  = (const float*)d_in[4];
  const float* b_dec  = (const float*)d_in[5];
  const float* W_agg  = (const float*)d_in[6];
  const float* b_agg  = (const float*)d_in[7];
  const float* W_attn = (const float*)d_in[8];
  const float* b_attn = (const float*)d_in[9];
  const float* conv_w = (const float*)d_in[10];
  const float* conv_b = (const float*)d_in[11];
  float* out = (float*)d_out;

  const long npix = (long)BB * HH * WW;               // 131072
  ushort_t* q_bf     = (ushort_t*)d_ws;               // [npix][64] bf16 NHWC
  ushort_t* k_bf     = q_bf + npix * 64;              // [npix][64]
  ushort_t* encw     = k_bf + npix * 64;              // [npix][64]  enc@W2
  ushort_t* dec_t    = encw + npix * 64;              // [npix][128]
  ushort_t* attw2    = dec_t + npix * 128;            // [npix][64]  attn@W2
  ushort_t* packedC2 = attw2 + npix * 64;             // composed conv W frags
  ushort_t* packedW2 = packedC2 + 144 * 64 * 8;       // W2 frags (8 blocks)
  ushort_t* packedQ  = packedW2 + 8 * 64 * 8;         // W_dec frags (16)
  ushort_t* packedK  = packedQ + 16 * 64 * 8;         // W_enc frags (8)
  float* bias_total  = (float*)(packedK + 8 * 64 * 8);// [64] f32

  hipLaunchKernelGGL(pack_w_kernel, dim3(177), dim3(64), 0, stream,
                     conv_w, W_attn, W_dec, W_enc, conv_b, b_attn,
                     packedC2, packedW2, packedQ, packedK, bias_total);
  hipLaunchKernelGGL(prep_kernel, dim3(BB * HH), dim3(256), 0, stream,
                     enc, dec, packedQ, packedK, packedW2, b_enc, b_dec,
                     q_bf, k_bf, encw, dec_t);
  hipLaunchKernelGGL(attn_kernel, dim3((int)(npix * 4 / 256)), dim3(256), 0, stream,
                     q_bf, k_bf, encw, W_agg, b_agg, attw2);
  hipLaunchKernelGGL(conv2_kernel, dim3(BB * HH), dim3(256), 0, stream,
                     dec_t, packedC2, attw2, bias_total, out);
}

// Round 17
// 120.509 us; speedup vs baseline: 1.7723x; 1.1286x over previous
//
#include <hip/hip_runtime.h>

#define BB 8
#define ENC_C 64
#define DEC_C 128
#define HH 128
#define WW 128

typedef unsigned short ushort_t;
typedef __attribute__((ext_vector_type(8))) short short8;
typedef __attribute__((ext_vector_type(4))) short short4v;
typedef __attribute__((ext_vector_type(4))) float f32x4;

static __device__ __forceinline__ ushort_t f2bf(float x) {
  unsigned int u = __builtin_bit_cast(unsigned int, x);
  u += 0x7fff + ((u >> 16) & 1);   // round-to-nearest-even
  return (ushort_t)(u >> 16);
}
static __device__ __forceinline__ float bf2f(ushort_t v) {
  unsigned int u = ((unsigned int)v) << 16;
  return __builtin_bit_cast(float, u);
}

// ---------------------------------------------------------------------------
// Kernel 0: pack weight fragments (bf16).
//   blk 0..143   : COMPOSED conv weights W' = conv_w @ W1  -> packedC2
//   blk 144..151 : W2 = W_attn rows 64..127 (K=64)         -> packedW2
//   blk 152..167 : W_dec  (K=128)                           -> packedQ
//   blk 168..175 : W_enc  (K=64)                            -> packedK
//   blk 176      : bias_total = conv_b @ W1 + b_attn (f32)
// Frag: lane l, elem j holds W[k = ks*32 + (l>>4)*8 + j][n = nf*16 + (l&15)].
// ---------------------------------------------------------------------------
__global__ __launch_bounds__(64) void pack_w_kernel(
    const float* __restrict__ conv_w, const float* __restrict__ W_attn,
    const float* __restrict__ W_dec, const float* __restrict__ W_enc,
    const float* __restrict__ conv_b, const float* __restrict__ b_attn,
    ushort_t* __restrict__ packedC2, ushort_t* __restrict__ packedW2,
    ushort_t* __restrict__ packedQ, ushort_t* __restrict__ packedK,
    float* __restrict__ bias_total)
{
  const int blk = blockIdx.x;
  const int l = threadIdx.x;

  if (blk < 144) {
    const int kstep = blk >> 2, nf = blk & 3;
    const int tap = kstep >> 2, dstep = kstep & 3;
    const int n = nf * 16 + (l & 15);
    const int dbase = dstep * 32 + (l >> 4) * 8;
    float wcol[64];
    #pragma unroll
    for (int c = 0; c < 64; ++c) wcol[c] = W_attn[c * 64 + n];
    ushort_t v[8];
    #pragma unroll
    for (int j = 0; j < 8; ++j) {
      const float* cw = conv_w + ((long)(tap * DEC_C + dbase + j)) * 64;
      float acc = 0.f;
      #pragma unroll
      for (int c = 0; c < 64; ++c) acc = __builtin_fmaf(cw[c], wcol[c], acc);
      v[j] = f2bf(acc);
    }
    ushort_t* d = packedC2 + (((long)tap * 16 + dstep * 4 + nf) * 64 + l) * 8;
    #pragma unroll
    for (int j = 0; j < 8; ++j) d[j] = v[j];
    return;
  }
  if (blk == 176) {
    float acc = b_attn[l];
    #pragma unroll
    for (int c = 0; c < 64; ++c)
      acc = __builtin_fmaf(conv_b[c], W_attn[c * 64 + l], acc);
    bias_total[l] = acc;
    return;
  }

  const float* W;
  ushort_t* dst;
  int bb, krow0;
  if (blk < 152)      { W = W_attn; dst = packedW2; bb = blk - 144; krow0 = 64; }
  else if (blk < 168) { W = W_dec;  dst = packedQ;  bb = blk - 152; krow0 = 0; }
  else                { W = W_enc;  dst = packedK;  bb = blk - 168; krow0 = 0; }
  const int ks = bb >> 2, nf = bb & 3;
  const int n = nf * 16 + (l & 15);
  const int kbase = krow0 + ks * 32 + (l >> 4) * 8;
  ushort_t v[8];
  #pragma unroll
  for (int j = 0; j < 8; ++j)
    v[j] = f2bf(W[(kbase + j) * 64 + n]);
  ushort_t* d = dst + ((long)bb * 64 + l) * 8;
  #pragma unroll
  for (int j = 0; j < 8; ++j) d[j] = v[j];
}

// ---------------------------------------------------------------------------
// Kernel 1: prep, WAVE-PRIVATE zero-barrier design. Grid 2048 = (b,h,half).
// Each wave owns a 16-pixel strip + private 4.35KB LDS region: no
// __syncthreads at all; 17.4KB/block -> 8 blocks = 32 waves/CU.
// All global loads row-contiguous; outputs q/k/encW NHWC bf16, dec_t NHWC.
// ---------------------------------------------------------------------------
__global__ __launch_bounds__(256) void prep_kernel(
    const float* __restrict__ enc, const float* __restrict__ dec,
    const ushort_t* __restrict__ packedQ, const ushort_t* __restrict__ packedK,
    const ushort_t* __restrict__ packedW2,
    const float* __restrict__ b_enc, const float* __restrict__ b_dec,
    ushort_t* __restrict__ q_nhwc, ushort_t* __restrict__ k_nhwc,
    ushort_t* __restrict__ encw, ushort_t* __restrict__ dec_t)
{
  __shared__ float smem[4 * 16 * 68];        // 17.4 KB, wave-private regions
  const int nwg = gridDim.x;                 // 2048, divisible by 8
  const int cpx = nwg >> 3;
  const int bid = blockIdx.x;
  const int grp = (bid & 7) * cpx + (bid >> 3);
  const int b = grp >> 8;
  const int h = (grp & 255) >> 1;
  const int half = grp & 1;
  const int bh = b * HH + h;
  const int tid = threadIdx.x;
  const int l = tid & 63;
  const int wv = tid >> 6;
  const int pw = half * 64 + wv * 16;        // wave's global pixel base
  const int col = l & 15, kg = l >> 4;
  const long plane = (long)HH * WW;
  float* swl = smem + wv * 16 * 68;          // wave-private [16px][68]

  // ================= enc phase: k = enc@W_enc + b, encW = enc@W2 ==========
  {
    // load 64ch x 16px (row-contiguous 64B segments, 4 ch/instruction)
    const float* ebase = enc + ((long)(b * ENC_C) * HH + h) * WW + pw;
    #pragma unroll
    for (int i = 0; i < 16; ++i) {
      const int cc = i * 4 + kg;
      swl[col * 68 + cc] = ebase[(long)cc * plane + col];
    }

    f32x4 acck[4], accw[4];
    #pragma unroll
    for (int nf = 0; nf < 4; ++nf) {
      acck[nf] = (f32x4){0.f, 0.f, 0.f, 0.f};
      accw[nf] = (f32x4){0.f, 0.f, 0.f, 0.f};
    }

    #pragma unroll
    for (int ks = 0; ks < 2; ++ks) {
      const float4* p = (const float4*)&swl[col * 68 + ks * 32 + kg * 8];
      float4 x0 = p[0], x1 = p[1];
      short8 afr;
      afr[0] = (short)f2bf(x0.x); afr[1] = (short)f2bf(x0.y);
      afr[2] = (short)f2bf(x0.z); afr[3] = (short)f2bf(x0.w);
      afr[4] = (short)f2bf(x1.x); afr[5] = (short)f2bf(x1.y);
      afr[6] = (short)f2bf(x1.z); afr[7] = (short)f2bf(x1.w);
      #pragma unroll
      for (int nf = 0; nf < 4; ++nf) {
        const short8 bk =
            *(const short8*)(packedK + ((long)(ks * 4 + nf) * 64 + l) * 8);
        const short8 bw =
            *(const short8*)(packedW2 + ((long)(ks * 4 + nf) * 64 + l) * 8);
        acck[nf] = __builtin_amdgcn_mfma_f32_16x16x32_bf16(
            afr, bk, acck[nf], 0, 0, 0);
        accw[nf] = __builtin_amdgcn_mfma_f32_16x16x32_bf16(
            afr, bw, accw[nf], 0, 0, 0);
      }
    }
    // store k and encW (NHWC bf16); D: pixel = kg*4+r, ch = nf*16+col
    #pragma unroll
    for (int nf = 0; nf < 4; ++nf)
      #pragma unroll
      for (int r = 0; r < 4; ++r) {
        const int px = pw + kg * 4 + r;
        const int c = nf * 16 + col;
        k_nhwc[((long)bh * WW + px) * 64 + c] = f2bf(acck[nf][r] + b_enc[c]);
        encw[((long)bh * WW + px) * 64 + c] = f2bf(accw[nf][r]);
      }
  }

  // ================= dec phase: dec_t + q (two 64-ch halves) ==============
  f32x4 accq[4];
  #pragma unroll
  for (int nf = 0; nf < 4; ++nf) accq[nf] = (f32x4){0.f, 0.f, 0.f, 0.f};

  #pragma unroll
  for (int hf = 0; hf < 2; ++hf) {
    const float* dbase =
        dec + ((long)(b * DEC_C + hf * 64) * HH + h) * WW + pw;
    #pragma unroll
    for (int i = 0; i < 16; ++i) {
      const int cc = i * 4 + kg;
      swl[col * 68 + cc] = dbase[(long)cc * plane + col];
    }

    // dec_t NHWC bf16: float4 LDS reads -> short4 stores (512B/instr)
    #pragma unroll
    for (int i = 0; i < 4; ++i) {
      const int px = kg + i * 4;
      const float4 v = *(const float4*)&swl[px * 68 + col * 4];
      short4v s;
      s[0] = (short)f2bf(v.x); s[1] = (short)f2bf(v.y);
      s[2] = (short)f2bf(v.z); s[3] = (short)f2bf(v.w);
      *(short4v*)(dec_t + ((long)bh * WW + pw + px) * DEC_C + hf * 64 + col * 4) = s;
    }

    // q MFMA
    #pragma unroll
    for (int ks2 = 0; ks2 < 2; ++ks2) {
      const int ks = hf * 2 + ks2;
      const float4* p = (const float4*)&swl[col * 68 + ks2 * 32 + kg * 8];
      float4 x0 = p[0], x1 = p[1];
      short8 afr;
      afr[0] = (short)f2bf(x0.x); afr[1] = (short)f2bf(x0.y);
      afr[2] = (short)f2bf(x0.z); afr[3] = (short)f2bf(x0.w);
      afr[4] = (short)f2bf(x1.x); afr[5] = (short)f2bf(x1.y);
      afr[6] = (short)f2bf(x1.z); afr[7] = (short)f2bf(x1.w);
      #pragma unroll
      for (int nf = 0; nf < 4; ++nf) {
        const short8 bfr =
            *(const short8*)(packedQ + ((long)(ks * 4 + nf) * 64 + l) * 8);
        accq[nf] = __builtin_amdgcn_mfma_f32_16x16x32_bf16(
            afr, bfr, accq[nf], 0, 0, 0);
      }
    }
  }

  // store q NHWC bf16
  #pragma unroll
  for (int nf = 0; nf < 4; ++nf)
    #pragma unroll
    for (int r = 0; r < 4; ++r) {
      const int px = pw + kg * 4 + r;
      const int c = nf * 16 + col;
      q_nhwc[((long)bh * WW + px) * 64 + c] = f2bf(accq[nf][r] + b_dec[c]);
    }
}

// ---------------------------------------------------------------------------
// Kernel 2: attention, FOUR threads per pixel (16 channels each).
// Weighted sum over encW (= enc@W2) -> output attW2 = attn_vec @ W2.
// ---------------------------------------------------------------------------
__global__ __launch_bounds__(256) void attn_kernel(
    const ushort_t* __restrict__ q_nhwc, const ushort_t* __restrict__ k_nhwc,
    const ushort_t* __restrict__ encw, const float* __restrict__ W_agg,
    const float* __restrict__ b_agg, ushort_t* __restrict__ attw2)
{
  const int nwg = gridDim.x;                 // 2048, divisible by 8
  const int cpx = nwg >> 3;
  const int bid = blockIdx.x;
  const int swz = (bid & 7) * cpx + (bid >> 3);   // XCD-contiguous pixels
  const int t = swz * 256 + threadIdx.x;     // 0 .. 4*npix-1
  const int pix = t >> 2;
  const int cb = (t & 3) * 16;               // this thread's channel base
  const int h = (pix >> 7) & 127;
  const int w = pix & 127;

  int off[9]; bool valid[9];
  #pragma unroll
  for (int n = 0; n < 9; ++n) {
    const int dh = n / 3 - 1, dw = n % 3 - 1;
    const int nh = h + dh, nw = w + dw;
    valid[n] = (nh >= 0 && nh < HH && nw >= 0 && nw < WW);
    const int nhc = min(max(nh, 0), HH - 1);
    const int nwc = min(max(nw, 0), WW - 1);
    off[n] = (pix & ~16383) + nhc * WW + nwc;  // same batch, clamped pixel
  }

  const short8* qp = (const short8*)(q_nhwc + ((long)pix << 6) + cb);
  const short8 qa = qp[0], qb = qp[1];

  float wa[16];
  {
    float4 w0 = *(const float4*)(W_agg + cb);
    float4 w1 = *(const float4*)(W_agg + cb + 4);
    float4 w2 = *(const float4*)(W_agg + cb + 8);
    float4 w3 = *(const float4*)(W_agg + cb + 12);
    wa[0]=w0.x; wa[1]=w0.y; wa[2]=w0.z; wa[3]=w0.w;
    wa[4]=w1.x; wa[5]=w1.y; wa[6]=w1.z; wa[7]=w1.w;
    wa[8]=w2.x; wa[9]=w2.y; wa[10]=w2.z; wa[11]=w2.w;
    wa[12]=w3.x; wa[13]=w3.y; wa[14]=w3.z; wa[15]=w3.w;
  }

  // ---- score partials over this thread's 16 channels ----
  float s[9];
  #pragma unroll
  for (int n = 0; n < 9; ++n) {
    const short8* kp = (const short8*)(k_nhwc + ((long)off[n] << 6) + cb);
    const short8 ka = kp[0], kb = kp[1];
    float sc = 0.f;
    #pragma unroll
    for (int e = 0; e < 8; ++e) {
      float x = bf2f((ushort_t)qa[e]) + bf2f((ushort_t)ka[e]);
      x = fminf(fmaxf(x, -15.f), 15.f);
      float z = __builtin_amdgcn_exp2f(x * 2.88539008f);
      float tt = __builtin_fmaf(-2.f, __builtin_amdgcn_rcpf(z + 1.f), 1.f);
      sc = __builtin_fmaf(tt, wa[e], sc);
    }
    #pragma unroll
    for (int e = 0; e < 8; ++e) {
      float x = bf2f((ushort_t)qb[e]) + bf2f((ushort_t)kb[e]);
      x = fminf(fmaxf(x, -15.f), 15.f);
      float z = __builtin_amdgcn_exp2f(x * 2.88539008f);
      float tt = __builtin_fmaf(-2.f, __builtin_amdgcn_rcpf(z + 1.f), 1.f);
      sc = __builtin_fmaf(tt, wa[8 + e], sc);
    }
    s[n] = sc;
  }

  // ---- combine partials across the 4 lanes of this pixel ----
  #pragma unroll
  for (int n = 0; n < 9; ++n) {
    s[n] += __shfl_xor(s[n], 1);
    s[n] += __shfl_xor(s[n], 2);
  }

  // ---- masked softmax (duplicated in all 4 lanes) ----
  const float bagg = b_agg[0];
  float m = -1e30f;
  #pragma unroll
  for (int n = 0; n < 9; ++n) {
    s[n] = valid[n] ? (s[n] + bagg) : -1e30f;
    m = fmaxf(m, s[n]);
  }
  float attw[9]; float denom = 0.f;
  #pragma unroll
  for (int n = 0; n < 9; ++n) {
    attw[n] = __builtin_amdgcn_exp2f((s[n] - m) * 1.44269504f);
    denom += attw[n];
  }
  const float inv = __builtin_amdgcn_rcpf(denom);
  #pragma unroll
  for (int n = 0; n < 9; ++n) attw[n] *= inv;   // invalid -> exactly 0

  // ---- weighted encW sum over this thread's 16 channels ----
  float a16[16];
  #pragma unroll
  for (int e = 0; e < 16; ++e) a16[e] = 0.f;
  #pragma unroll
  for (int n = 0; n < 9; ++n) {
    const short8* ep = (const short8*)(encw + ((long)off[n] << 6) + cb);
    const short8 ea = ep[0], eb = ep[1];
    #pragma unroll
    for (int e = 0; e < 8; ++e)
      a16[e] = __builtin_fmaf(attw[n], bf2f((ushort_t)ea[e]), a16[e]);
    #pragma unroll
    for (int e = 0; e < 8; ++e)
      a16[8 + e] = __builtin_fmaf(attw[n], bf2f((ushort_t)eb[e]), a16[8 + e]);
  }
  short8 o0, o1;
  #pragma unroll
  for (int e = 0; e < 8; ++e) {
    o0[e] = (short)f2bf(a16[e]);
    o1[e] = (short)f2bf(a16[8 + e]);
  }
  short8* op = (short8*)(attw2 + ((long)pix << 6) + cb);
  op[0] = o0;
  op[1] = o1;
}

// ---------------------------------------------------------------------------
// Kernel 3: conv with COMPOSED weights, swapped MFMA (A = W' frags from
// staged LDS, B = pixel frags from global) -> D = (ch, pix). One row/block
// (grid 1024), 9-phase dbuf async staging. Epilogue: + attW2 + bias_total,
// LeakyReLU, direct coalesced NCHW store. LDS 32 KB.
// ---------------------------------------------------------------------------
__global__ __launch_bounds__(256) void conv2_kernel(
    const ushort_t* __restrict__ dec_t, const ushort_t* __restrict__ packedC2,
    const ushort_t* __restrict__ attw2, const float* __restrict__ bias_total,
    float* __restrict__ out)
{
  __shared__ ushort_t bsh[16384];            // 32 KB: 2 x 16KB tap buffers
  const int nwg = gridDim.x;                 // 1024, divisible by 8
  const int cpx = nwg >> 3;
  const int bid = blockIdx.x;
  const int bh = (bid & 7) * cpx + (bid >> 3);
  const int b = bh >> 7, h = bh & 127;
  const int tid = threadIdx.x;
  const int l = tid & 63;
  const int wv = tid >> 6;
  const int pix0 = wv * 32;
  const int col = l & 15, kg = l >> 4;

  auto stage = [&](int tap) {
    const ushort_t* src = packedC2 + (long)tap * 8192;
    ushort_t* dstb = bsh + (tap & 1) * 8192 + (long)(tid & ~63) * 8;
    #pragma unroll
    for (int i = 0; i < 4; ++i) {
      __builtin_amdgcn_global_load_lds(
          (const __attribute__((address_space(1))) void*)(src + (long)(i * 256 + tid) * 8),
          (__attribute__((address_space(3))) void*)(dstb + i * 256 * 8),
          16, 0, 0);
    }
  };

  f32x4 acc[4][2];                           // [ch frag mf][pix frag pf]
  #pragma unroll
  for (int mf = 0; mf < 4; ++mf)
    #pragma unroll
    for (int pf = 0; pf < 2; ++pf)
      acc[mf][pf] = (f32x4){0.f, 0.f, 0.f, 0.f};

  stage(0);

  #pragma unroll
  for (int p = 0; p < 9; ++p) {
    __syncthreads();                         // buf[p&1] staged; prior reads done
    if (p + 1 < 9) stage(p + 1);             // async loads fly across compute
    const int kh = p / 3, kw = p % 3;
    const int hh = h + kh - 1;
    if (hh >= 0 && hh < HH) {                // block-uniform skip
      const ushort_t* arow = dec_t + ((long)(b * HH + hh) * WW) * DEC_C;
      const ushort_t* bbase = bsh + (p & 1) * 8192;
      short8 pfr[4][2];
      #pragma unroll
      for (int pf = 0; pf < 2; ++pf) {
        const int wp = pix0 + pf * 16 + col + kw - 1;
        const bool ok = (wp >= 0 && wp < WW);
        #pragma unroll
        for (int ds = 0; ds < 4; ++ds) {
          short8 z = {0, 0, 0, 0, 0, 0, 0, 0};
          pfr[ds][pf] = ok
              ? *(const short8*)(arow + (long)wp * DEC_C + ds * 32 + kg * 8) : z;
        }
      }
      #pragma unroll
      for (int ds = 0; ds < 4; ++ds)
        #pragma unroll
        for (int mf = 0; mf < 4; ++mf) {
          const short8 wfr =
              *(const short8*)(bbase + ((ds * 4 + mf) * 64 + l) * 8);
          acc[mf][0] = __builtin_amdgcn_mfma_f32_16x16x32_bf16(
              wfr, pfr[ds][0], acc[mf][0], 0, 0, 0);
          acc[mf][1] = __builtin_amdgcn_mfma_f32_16x16x32_bf16(
              wfr, pfr[ds][1], acc[mf][1], 0, 0, 0);
        }
    }
  }

  // ---- epilogue: + attW2 + bias_total, LeakyReLU, NCHW store ----
  #pragma unroll
  for (int mf = 0; mf < 4; ++mf)
    #pragma unroll
    for (int pf = 0; pf < 2; ++pf) {
      const int pix = pix0 + pf * 16 + col;
      const short4v av = *(const short4v*)(
          attw2 + ((long)bh * WW + pix) * 64 + mf * 16 + kg * 4);
      #pragma unroll
      for (int r = 0; r < 4; ++r) {
        const int ch = mf * 16 + kg * 4 + r;
        float o = acc[mf][pf][r] + bf2f((ushort_t)av[r]) + bias_total[ch];
        o = (o >= 0.f) ? o : 0.2f * o;
        out[((long)(b * ENC_C + ch) * HH + h) * WW + pix] = o;
      }
    }
}

// ---------------------------------------------------------------------------
extern "C" void kernel_launch(void* const* d_in, const int* in_sizes, int n_in,
                              void* d_out, int out_size, void* d_ws, size_t ws_size,
                              hipStream_t stream) {
  const float* enc    = (const float*)d_in[0];
  const float* dec    = (const float*)d_in[1];
  const float* W_enc  = (const float*)d_in[2];
  const float* b_enc  = (const float*)d_in[3];
  const float* W_dec  = (const float*)d_in[4];
  const float* b_dec  = (const float*)d_in[5];
  const float* W_agg  = (const float*)d_in[6];
  const float* b_agg  = (const float*)d_in[7];
  const float* W_attn = (const float*)d_in[8];
  const float* b_attn = (const float*)d_in[9];
  const float* conv_w = (const float*)d_in[10];
  const float* conv_b = (const float*)d_in[11];
  float* out = (float*)d_out;

  const long npix = (long)BB * HH * WW;               // 131072
  ushort_t* q_bf     = (ushort_t*)d_ws;               // [npix][64] bf16 NHWC
  ushort_t* k_bf     = q_bf + npix * 64;              // [npix][64]
  ushort_t* encw     = k_bf + npix * 64;              // [npix][64]  enc@W2
  ushort_t* dec_t    = encw + npix * 64;              // [npix][128]
  ushort_t* attw2    = dec_t + npix * 128;            // [npix][64]  attn@W2
  ushort_t* packedC2 = attw2 + npix * 64;             // composed conv W frags
  ushort_t* packedW2 = packedC2 + 144 * 64 * 8;       // W2 frags (8 blocks)
  ushort_t* packedQ  = packedW2 + 8 * 64 * 8;         // W_dec frags (16)
  ushort_t* packedK  = packedQ + 16 * 64 * 8;         // W_enc frags (8)
  float* bias_total  = (float*)(packedK + 8 * 64 * 8);// [64] f32

  hipLaunchKernelGGL(pack_w_kernel, dim3(177), dim3(64), 0, stream,
                     conv_w, W_attn, W_dec, W_enc, conv_b, b_attn,
                     packedC2, packedW2, packedQ, packedK, bias_total);
  hipLaunchKernelGGL(prep_kernel, dim3(BB * HH * 2), dim3(256), 0, stream,
                     enc, dec, packedQ, packedK, packedW2, b_enc, b_dec,
                     q_bf, k_bf, encw, dec_t);
  hipLaunchKernelGGL(attn_kernel, dim3((int)(npix * 4 / 256)), dim3(256), 0, stream,
                     q_bf, k_bf, encw, W_agg, b_agg, attw2);
  hipLaunchKernelGGL(conv2_kernel, dim3(BB * HH), dim3(256), 0, stream,
                     dec_t, packedC2, attw2, bias_total, out);
}

// Round 18
// 120.179 us; speedup vs baseline: 1.7771x; 1.0027x over previous
//
#include <hip/hip_runtime.h>

#define BB 8
#define ENC_C 64
#define DEC_C 128
#define HH 128
#define WW 128

typedef unsigned short ushort_t;
typedef __attribute__((ext_vector_type(8))) short short8;
typedef __attribute__((ext_vector_type(4))) short short4v;
typedef __attribute__((ext_vector_type(4))) float f32x4;

static __device__ __forceinline__ ushort_t f2bf(float x) {
  unsigned int u = __builtin_bit_cast(unsigned int, x);
  u += 0x7fff + ((u >> 16) & 1);   // round-to-nearest-even
  return (ushort_t)(u >> 16);
}
static __device__ __forceinline__ float bf2f(ushort_t v) {
  unsigned int u = ((unsigned int)v) << 16;
  return __builtin_bit_cast(float, u);
}

// ---------------------------------------------------------------------------
// Kernel 0: pack weight fragments (bf16).
//   blk 0..143   : COMPOSED conv weights W' = conv_w @ W1  -> packedC2
//   blk 144..151 : W2 = W_attn rows 64..127 (K=64)         -> packedW2
//   blk 152..167 : W_dec  (K=128)                           -> packedQ
//   blk 168..175 : W_enc  (K=64)                            -> packedK
//   blk 176      : bias_total = conv_b @ W1 + b_attn (f32)
// Frag: lane l, elem j holds W[k = ks*32 + (l>>4)*8 + j][n = nf*16 + (l&15)].
// ---------------------------------------------------------------------------
__global__ __launch_bounds__(64) void pack_w_kernel(
    const float* __restrict__ conv_w, const float* __restrict__ W_attn,
    const float* __restrict__ W_dec, const float* __restrict__ W_enc,
    const float* __restrict__ conv_b, const float* __restrict__ b_attn,
    ushort_t* __restrict__ packedC2, ushort_t* __restrict__ packedW2,
    ushort_t* __restrict__ packedQ, ushort_t* __restrict__ packedK,
    float* __restrict__ bias_total)
{
  const int blk = blockIdx.x;
  const int l = threadIdx.x;

  if (blk < 144) {
    const int kstep = blk >> 2, nf = blk & 3;
    const int tap = kstep >> 2, dstep = kstep & 3;
    const int n = nf * 16 + (l & 15);
    const int dbase = dstep * 32 + (l >> 4) * 8;
    float wcol[64];
    #pragma unroll
    for (int c = 0; c < 64; ++c) wcol[c] = W_attn[c * 64 + n];
    ushort_t v[8];
    #pragma unroll
    for (int j = 0; j < 8; ++j) {
      const float* cw = conv_w + ((long)(tap * DEC_C + dbase + j)) * 64;
      float acc = 0.f;
      #pragma unroll
      for (int c = 0; c < 64; ++c) acc = __builtin_fmaf(cw[c], wcol[c], acc);
      v[j] = f2bf(acc);
    }
    ushort_t* d = packedC2 + (((long)tap * 16 + dstep * 4 + nf) * 64 + l) * 8;
    #pragma unroll
    for (int j = 0; j < 8; ++j) d[j] = v[j];
    return;
  }
  if (blk == 176) {
    float acc = b_attn[l];
    #pragma unroll
    for (int c = 0; c < 64; ++c)
      acc = __builtin_fmaf(conv_b[c], W_attn[c * 64 + l], acc);
    bias_total[l] = acc;
    return;
  }

  const float* W;
  ushort_t* dst;
  int bb, krow0;
  if (blk < 152)      { W = W_attn; dst = packedW2; bb = blk - 144; krow0 = 64; }
  else if (blk < 168) { W = W_dec;  dst = packedQ;  bb = blk - 152; krow0 = 0; }
  else                { W = W_enc;  dst = packedK;  bb = blk - 168; krow0 = 0; }
  const int ks = bb >> 2, nf = bb & 3;
  const int n = nf * 16 + (l & 15);
  const int kbase = krow0 + ks * 32 + (l >> 4) * 8;
  ushort_t v[8];
  #pragma unroll
  for (int j = 0; j < 8; ++j)
    v[j] = f2bf(W[(kbase + j) * 64 + n]);
  ushort_t* d = dst + ((long)bb * 64 + l) * 8;
  #pragma unroll
  for (int j = 0; j < 8; ++j) d[j] = v[j];
}

// ---------------------------------------------------------------------------
// Kernel 1: prep, wave-private zero-barrier, VECTORIZED memory.
// Grid 2048 = (b,h,half); wave owns 16-pixel strip + 2 private LDS buffers
// (8.7KB/wave, 34.8KB/block). float4 global loads (1KB/instr), short8
// stores via LDS repack (64B segments). (256,2): VGPR ceiling 256 so the
// compiler can keep both tiles' loads in flight (R17 showed it self-caps
// at 64 VGPR otherwise).
// ---------------------------------------------------------------------------
__global__ __launch_bounds__(256, 2) void prep_kernel(
    const float* __restrict__ enc, const float* __restrict__ dec,
    const ushort_t* __restrict__ packedQ, const ushort_t* __restrict__ packedK,
    const ushort_t* __restrict__ packedW2,
    const float* __restrict__ b_enc, const float* __restrict__ b_dec,
    ushort_t* __restrict__ q_nhwc, ushort_t* __restrict__ k_nhwc,
    ushort_t* __restrict__ encw, ushort_t* __restrict__ dec_t)
{
  __shared__ float smem[4 * 2 * 16 * 68];    // 34.8 KB
  const int nwg = gridDim.x;                 // 2048, divisible by 8
  const int cpx = nwg >> 3;
  const int bid = blockIdx.x;
  const int grp = (bid & 7) * cpx + (bid >> 3);
  const int b = grp >> 8;
  const int h = (grp & 255) >> 1;
  const int half = grp & 1;
  const int bh = b * HH + h;
  const int tid = threadIdx.x;
  const int l = tid & 63;
  const int wv = tid >> 6;
  const int pw = half * 64 + wv * 16;        // wave's global pixel base
  const int col = l & 15, kg = l >> 4;
  const int a4 = l & 3, c16 = l >> 2;
  const long plane = (long)HH * WW;
  float* bufA = smem + wv * 2 * 1088;        // [16px][68ch]
  float* bufB = bufA + 1088;

  // float4 loads over w: 16 planes x 64B = 1KB per instruction
  auto load_tile = [&](const float* base, float* buf) {
    #pragma unroll
    for (int it = 0; it < 4; ++it) {
      const int p = it * 16 + c16;
      const float4 v = *(const float4*)(base + (long)p * plane + a4 * 4);
      buf[(a4 * 4 + 0) * 68 + p] = v.x;
      buf[(a4 * 4 + 1) * 68 + p] = v.y;
      buf[(a4 * 4 + 2) * 68 + p] = v.z;
      buf[(a4 * 4 + 3) * 68 + p] = v.w;
    }
  };
  auto make_frag = [&](const float* buf, int koff) -> short8 {
    const float4 x0 = *(const float4*)&buf[col * 68 + koff];
    const float4 x1 = *(const float4*)&buf[col * 68 + koff + 4];
    short8 v;
    v[0] = (short)f2bf(x0.x); v[1] = (short)f2bf(x0.y);
    v[2] = (short)f2bf(x0.z); v[3] = (short)f2bf(x0.w);
    v[4] = (short)f2bf(x1.x); v[5] = (short)f2bf(x1.y);
    v[6] = (short)f2bf(x1.z); v[7] = (short)f2bf(x1.w);
    return v;
  };
  // acc -> LDS repack -> short8 stores (16px x 128B, 64B segments)
  auto repack_store = [&](const f32x4* acc, const float* bias, ushort_t* dst,
                          float* buf) {
    #pragma unroll
    for (int nf = 0; nf < 4; ++nf) {
      const float bb = bias ? bias[nf * 16 + col] : 0.f;
      #pragma unroll
      for (int r = 0; r < 4; ++r)
        buf[(kg * 4 + r) * 68 + nf * 16 + col] = acc[nf][r] + bb;
    }
    #pragma unroll
    for (int j = 0; j < 2; ++j) {
      const int px = c16;
      const int c8 = (a4 + 4 * j) * 8;
      const float4 x0 = *(const float4*)&buf[px * 68 + c8];
      const float4 x1 = *(const float4*)&buf[px * 68 + c8 + 4];
      short8 s;
      s[0] = (short)f2bf(x0.x); s[1] = (short)f2bf(x0.y);
      s[2] = (short)f2bf(x0.z); s[3] = (short)f2bf(x0.w);
      s[4] = (short)f2bf(x1.x); s[5] = (short)f2bf(x1.y);
      s[6] = (short)f2bf(x1.z); s[7] = (short)f2bf(x1.w);
      *(short8*)(dst + (((long)(bh * WW + pw + px)) << 6) + c8) = s;
    }
  };
  // dec_t: straight from the f32 tile buffer
  auto dect_store = [&](const float* buf, int hf) {
    #pragma unroll
    for (int j = 0; j < 2; ++j) {
      const int px = c16;
      const int c8 = (a4 + 4 * j) * 8;
      const float4 x0 = *(const float4*)&buf[px * 68 + c8];
      const float4 x1 = *(const float4*)&buf[px * 68 + c8 + 4];
      short8 s;
      s[0] = (short)f2bf(x0.x); s[1] = (short)f2bf(x0.y);
      s[2] = (short)f2bf(x0.z); s[3] = (short)f2bf(x0.w);
      s[4] = (short)f2bf(x1.x); s[5] = (short)f2bf(x1.y);
      s[6] = (short)f2bf(x1.z); s[7] = (short)f2bf(x1.w);
      *(short8*)(dec_t + (((long)(bh * WW + pw + px)) << 7) + hf * 64 + c8) = s;
    }
  };

  f32x4 acck[4], accw[4], accq[4];
  #pragma unroll
  for (int nf = 0; nf < 4; ++nf) {
    acck[nf] = (f32x4){0.f, 0.f, 0.f, 0.f};
    accw[nf] = (f32x4){0.f, 0.f, 0.f, 0.f};
    accq[nf] = (f32x4){0.f, 0.f, 0.f, 0.f};
  }

  // 1) issue enc -> bufA and dec half0 -> bufB (both tile loads in flight)
  load_tile(enc + ((long)(b * ENC_C) * HH + h) * WW + pw, bufA);
  load_tile(dec + ((long)(b * DEC_C) * HH + h) * WW + pw, bufB);

  // 2) enc MFMAs: k = enc@W_enc, encW = enc@W2
  #pragma unroll
  for (int ks = 0; ks < 2; ++ks) {
    const short8 afr = make_frag(bufA, ks * 32 + kg * 8);
    #pragma unroll
    for (int nf = 0; nf < 4; ++nf) {
      const short8 bk =
          *(const short8*)(packedK + ((long)(ks * 4 + nf) * 64 + l) * 8);
      const short8 bw =
          *(const short8*)(packedW2 + ((long)(ks * 4 + nf) * 64 + l) * 8);
      acck[nf] = __builtin_amdgcn_mfma_f32_16x16x32_bf16(afr, bk, acck[nf], 0, 0, 0);
      accw[nf] = __builtin_amdgcn_mfma_f32_16x16x32_bf16(afr, bw, accw[nf], 0, 0, 0);
    }
  }

  // 3) dec half1 -> bufA (frag reads done; DS ops are wave-ordered)
  load_tile(dec + ((long)(b * DEC_C + 64) * HH + h) * WW + pw, bufA);

  // 4) dec half0: q MFMAs + dec_t
  #pragma unroll
  for (int ks2 = 0; ks2 < 2; ++ks2) {
    const short8 afr = make_frag(bufB, ks2 * 32 + kg * 8);
    #pragma unroll
    for (int nf = 0; nf < 4; ++nf) {
      const short8 bq =
          *(const short8*)(packedQ + ((long)(ks2 * 4 + nf) * 64 + l) * 8);
      accq[nf] = __builtin_amdgcn_mfma_f32_16x16x32_bf16(afr, bq, accq[nf], 0, 0, 0);
    }
  }
  dect_store(bufB, 0);

  // 5) k / encW repack + store (bufB reusable after its reads)
  repack_store(acck, b_enc, k_nhwc, bufB);
  repack_store(accw, nullptr, encw, bufB);

  // 6) dec half1: q MFMAs + dec_t
  #pragma unroll
  for (int ks2 = 0; ks2 < 2; ++ks2) {
    const short8 afr = make_frag(bufA, ks2 * 32 + kg * 8);
    #pragma unroll
    for (int nf = 0; nf < 4; ++nf) {
      const short8 bq =
          *(const short8*)(packedQ + ((long)((2 + ks2) * 4 + nf) * 64 + l) * 8);
      accq[nf] = __builtin_amdgcn_mfma_f32_16x16x32_bf16(afr, bq, accq[nf], 0, 0, 0);
    }
  }
  dect_store(bufA, 1);

  // 7) q repack + store
  repack_store(accq, b_dec, q_nhwc, bufA);
}

// ---------------------------------------------------------------------------
// Kernel 2: attention, FOUR threads per pixel (16 channels each).
// Weighted sum over encW (= enc@W2) -> output attW2 = attn_vec @ W2.
// ---------------------------------------------------------------------------
__global__ __launch_bounds__(256) void attn_kernel(
    const ushort_t* __restrict__ q_nhwc, const ushort_t* __restrict__ k_nhwc,
    const ushort_t* __restrict__ encw, const float* __restrict__ W_agg,
    const float* __restrict__ b_agg, ushort_t* __restrict__ attw2)
{
  const int nwg = gridDim.x;                 // 2048, divisible by 8
  const int cpx = nwg >> 3;
  const int bid = blockIdx.x;
  const int swz = (bid & 7) * cpx + (bid >> 3);   // XCD-contiguous pixels
  const int t = swz * 256 + threadIdx.x;     // 0 .. 4*npix-1
  const int pix = t >> 2;
  const int cb = (t & 3) * 16;               // this thread's channel base
  const int h = (pix >> 7) & 127;
  const int w = pix & 127;

  int off[9]; bool valid[9];
  #pragma unroll
  for (int n = 0; n < 9; ++n) {
    const int dh = n / 3 - 1, dw = n % 3 - 1;
    const int nh = h + dh, nw = w + dw;
    valid[n] = (nh >= 0 && nh < HH && nw >= 0 && nw < WW);
    const int nhc = min(max(nh, 0), HH - 1);
    const int nwc = min(max(nw, 0), WW - 1);
    off[n] = (pix & ~16383) + nhc * WW + nwc;  // same batch, clamped pixel
  }

  const short8* qp = (const short8*)(q_nhwc + ((long)pix << 6) + cb);
  const short8 qa = qp[0], qb = qp[1];

  float wa[16];
  {
    float4 w0 = *(const float4*)(W_agg + cb);
    float4 w1 = *(const float4*)(W_agg + cb + 4);
    float4 w2 = *(const float4*)(W_agg + cb + 8);
    float4 w3 = *(const float4*)(W_agg + cb + 12);
    wa[0]=w0.x; wa[1]=w0.y; wa[2]=w0.z; wa[3]=w0.w;
    wa[4]=w1.x; wa[5]=w1.y; wa[6]=w1.z; wa[7]=w1.w;
    wa[8]=w2.x; wa[9]=w2.y; wa[10]=w2.z; wa[11]=w2.w;
    wa[12]=w3.x; wa[13]=w3.y; wa[14]=w3.z; wa[15]=w3.w;
  }

  // ---- score partials over this thread's 16 channels ----
  float s[9];
  #pragma unroll
  for (int n = 0; n < 9; ++n) {
    const short8* kp = (const short8*)(k_nhwc + ((long)off[n] << 6) + cb);
    const short8 ka = kp[0], kb = kp[1];
    float sc = 0.f;
    #pragma unroll
    for (int e = 0; e < 8; ++e) {
      float x = bf2f((ushort_t)qa[e]) + bf2f((ushort_t)ka[e]);
      x = fminf(fmaxf(x, -15.f), 15.f);
      float z = __builtin_amdgcn_exp2f(x * 2.88539008f);
      float tt = __builtin_fmaf(-2.f, __builtin_amdgcn_rcpf(z + 1.f), 1.f);
      sc = __builtin_fmaf(tt, wa[e], sc);
    }
    #pragma unroll
    for (int e = 0; e < 8; ++e) {
      float x = bf2f((ushort_t)qb[e]) + bf2f((ushort_t)kb[e]);
      x = fminf(fmaxf(x, -15.f), 15.f);
      float z = __builtin_amdgcn_exp2f(x * 2.88539008f);
      float tt = __builtin_fmaf(-2.f, __builtin_amdgcn_rcpf(z + 1.f), 1.f);
      sc = __builtin_fmaf(tt, wa[8 + e], sc);
    }
    s[n] = sc;
  }

  // ---- combine partials across the 4 lanes of this pixel ----
  #pragma unroll
  for (int n = 0; n < 9; ++n) {
    s[n] += __shfl_xor(s[n], 1);
    s[n] += __shfl_xor(s[n], 2);
  }

  // ---- masked softmax (duplicated in all 4 lanes) ----
  const float bagg = b_agg[0];
  float m = -1e30f;
  #pragma unroll
  for (int n = 0; n < 9; ++n) {
    s[n] = valid[n] ? (s[n] + bagg) : -1e30f;
    m = fmaxf(m, s[n]);
  }
  float attw[9]; float denom = 0.f;
  #pragma unroll
  for (int n = 0; n < 9; ++n) {
    attw[n] = __builtin_amdgcn_exp2f((s[n] - m) * 1.44269504f);
    denom += attw[n];
  }
  const float inv = __builtin_amdgcn_rcpf(denom);
  #pragma unroll
  for (int n = 0; n < 9; ++n) attw[n] *= inv;   // invalid -> exactly 0

  // ---- weighted encW sum over this thread's 16 channels ----
  float a16[16];
  #pragma unroll
  for (int e = 0; e < 16; ++e) a16[e] = 0.f;
  #pragma unroll
  for (int n = 0; n < 9; ++n) {
    const short8* ep = (const short8*)(encw + ((long)off[n] << 6) + cb);
    const short8 ea = ep[0], eb = ep[1];
    #pragma unroll
    for (int e = 0; e < 8; ++e)
      a16[e] = __builtin_fmaf(attw[n], bf2f((ushort_t)ea[e]), a16[e]);
    #pragma unroll
    for (int e = 0; e < 8; ++e)
      a16[8 + e] = __builtin_fmaf(attw[n], bf2f((ushort_t)eb[e]), a16[8 + e]);
  }
  short8 o0, o1;
  #pragma unroll
  for (int e = 0; e < 8; ++e) {
    o0[e] = (short)f2bf(a16[e]);
    o1[e] = (short)f2bf(a16[8 + e]);
  }
  short8* op = (short8*)(attw2 + ((long)pix << 6) + cb);
  op[0] = o0;
  op[1] = o1;
}

// ---------------------------------------------------------------------------
// Kernel 3: conv with COMPOSED weights, swapped MFMA (A = W' frags from
// staged LDS, B = pixel frags from global) -> D = (ch, pix). One row/block
// (grid 1024), 9-phase dbuf async staging. Epilogue: + attW2 + bias_total,
// LeakyReLU, direct coalesced NCHW store. LDS 32 KB.
// ---------------------------------------------------------------------------
__global__ __launch_bounds__(256) void conv2_kernel(
    const ushort_t* __restrict__ dec_t, const ushort_t* __restrict__ packedC2,
    const ushort_t* __restrict__ attw2, const float* __restrict__ bias_total,
    float* __restrict__ out)
{
  __shared__ ushort_t bsh[16384];            // 32 KB: 2 x 16KB tap buffers
  const int nwg = gridDim.x;                 // 1024, divisible by 8
  const int cpx = nwg >> 3;
  const int bid = blockIdx.x;
  const int bh = (bid & 7) * cpx + (bid >> 3);
  const int b = bh >> 7, h = bh & 127;
  const int tid = threadIdx.x;
  const int l = tid & 63;
  const int wv = tid >> 6;
  const int pix0 = wv * 32;
  const int col = l & 15, kg = l >> 4;

  auto stage = [&](int tap) {
    const ushort_t* src = packedC2 + (long)tap * 8192;
    ushort_t* dstb = bsh + (tap & 1) * 8192 + (long)(tid & ~63) * 8;
    #pragma unroll
    for (int i = 0; i < 4; ++i) {
      __builtin_amdgcn_global_load_lds(
          (const __attribute__((address_space(1))) void*)(src + (long)(i * 256 + tid) * 8),
          (__attribute__((address_space(3))) void*)(dstb + i * 256 * 8),
          16, 0, 0);
    }
  };

  f32x4 acc[4][2];                           // [ch frag mf][pix frag pf]
  #pragma unroll
  for (int mf = 0; mf < 4; ++mf)
    #pragma unroll
    for (int pf = 0; pf < 2; ++pf)
      acc[mf][pf] = (f32x4){0.f, 0.f, 0.f, 0.f};

  stage(0);

  #pragma unroll
  for (int p = 0; p < 9; ++p) {
    __syncthreads();                         // buf[p&1] staged; prior reads done
    if (p + 1 < 9) stage(p + 1);             // async loads fly across compute
    const int kh = p / 3, kw = p % 3;
    const int hh = h + kh - 1;
    if (hh >= 0 && hh < HH) {                // block-uniform skip
      const ushort_t* arow = dec_t + ((long)(b * HH + hh) * WW) * DEC_C;
      const ushort_t* bbase = bsh + (p & 1) * 8192;
      short8 pfr[4][2];
      #pragma unroll
      for (int pf = 0; pf < 2; ++pf) {
        const int wp = pix0 + pf * 16 + col + kw - 1;
        const bool ok = (wp >= 0 && wp < WW);
        #pragma unroll
        for (int ds = 0; ds < 4; ++ds) {
          short8 z = {0, 0, 0, 0, 0, 0, 0, 0};
          pfr[ds][pf] = ok
              ? *(const short8*)(arow + (long)wp * DEC_C + ds * 32 + kg * 8) : z;
        }
      }
      #pragma unroll
      for (int ds = 0; ds < 4; ++ds)
        #pragma unroll
        for (int mf = 0; mf < 4; ++mf) {
          const short8 wfr =
              *(const short8*)(bbase + ((ds * 4 + mf) * 64 + l) * 8);
          acc[mf][0] = __builtin_amdgcn_mfma_f32_16x16x32_bf16(
              wfr, pfr[ds][0], acc[mf][0], 0, 0, 0);
          acc[mf][1] = __builtin_amdgcn_mfma_f32_16x16x32_bf16(
              wfr, pfr[ds][1], acc[mf][1], 0, 0, 0);
        }
    }
  }

  // ---- epilogue: + attW2 + bias_total, LeakyReLU, NCHW store ----
  #pragma unroll
  for (int mf = 0; mf < 4; ++mf)
    #pragma unroll
    for (int pf = 0; pf < 2; ++pf) {
      const int pix = pix0 + pf * 16 + col;
      const short4v av = *(const short4v*)(
          attw2 + ((long)bh * WW + pix) * 64 + mf * 16 + kg * 4);
      #pragma unroll
      for (int r = 0; r < 4; ++r) {
        const int ch = mf * 16 + kg * 4 + r;
        float o = acc[mf][pf][r] + bf2f((ushort_t)av[r]) + bias_total[ch];
        o = (o >= 0.f) ? o : 0.2f * o;
        out[((long)(b * ENC_C + ch) * HH + h) * WW + pix] = o;
      }
    }
}

// ---------------------------------------------------------------------------
extern "C" void kernel_launch(void* const* d_in, const int* in_sizes, int n_in,
                              void* d_out, int out_size, void* d_ws, size_t ws_size,
                              hipStream_t stream) {
  const float* enc    = (const float*)d_in[0];
  const float* dec    = (const float*)d_in[1];
  const float* W_enc  = (const float*)d_in[2];
  const float* b_enc  = (const float*)d_in[3];
  const float* W_dec  = (const float*)d_in[4];
  const float* b_dec  = (const float*)d_in[5];
  const float* W_agg  = (const float*)d_in[6];
  const float* b_agg  = (const float*)d_in[7];
  const float* W_attn = (const float*)d_in[8];
  const float* b_attn = (const float*)d_in[9];
  const float* conv_w = (const float*)d_in[10];
  const float* conv_b = (const float*)d_in[11];
  float* out = (float*)d_out;

  const long npix = (long)BB * HH * WW;               // 131072
  ushort_t* q_bf     = (ushort_t*)d_ws;               // [npix][64] bf16 NHWC
  ushort_t* k_bf     = q_bf + npix * 64;              // [npix][64]
  ushort_t* encw     = k_bf + npix * 64;              // [npix][64]  enc@W2
  ushort_t* dec_t    = encw + npix * 64;              // [npix][128]
  ushort_t* attw2    = dec_t + npix * 128;            // [npix][64]  attn@W2
  ushort_t* packedC2 = attw2 + npix * 64;             // composed conv W frags
  ushort_t* packedW2 = packedC2 + 144 * 64 * 8;       // W2 frags (8 blocks)
  ushort_t* packedQ  = packedW2 + 8 * 64 * 8;         // W_dec frags (16)
  ushort_t* packedK  = packedQ + 16 * 64 * 8;         // W_enc frags (8)
  float* bias_total  = (float*)(packedK + 8 * 64 * 8);// [64] f32

  hipLaunchKernelGGL(pack_w_kernel, dim3(177), dim3(64), 0, stream,
                     conv_w, W_attn, W_dec, W_enc, conv_b, b_attn,
                     packedC2, packedW2, packedQ, packedK, bias_total);
  hipLaunchKernelGGL(prep_kernel, dim3(BB * HH * 2), dim3(256), 0, stream,
                     enc, dec, packedQ, packedK, packedW2, b_enc, b_dec,
                     q_bf, k_bf, encw, dec_t);
  hipLaunchKernelGGL(attn_kernel, dim3((int)(npix * 4 / 256)), dim3(256), 0, stream,
                     q_bf, k_bf, encw, W_agg, b_agg, attw2);
  hipLaunchKernelGGL(conv2_kernel, dim3(BB * HH), dim3(256), 0, stream,
                     dec_t, packedC2, attw2, bias_total, out);
}